// Round 12
// baseline (305.259 us; speedup 1.0000x reference)
//
#include <hip/hip_runtime.h>
#include <hip/hip_bf16.h>
#include <math.h>

#define BATCH 16384
#define NCAT 24

// log(1e-30f), log(16)
#define L30F  (-69.07755279f)
#define LOGKF (2.7725887f)

typedef __attribute__((ext_vector_type(8))) short short8;
typedef __attribute__((ext_vector_type(4))) float f32x4;

__device__ __forceinline__ float lae(float a, float b) {
    float m = fmaxf(a, b);
    return m + logf(expf(a - m) + expf(b - m));
}

__device__ __forceinline__ void glds16(const void* g, void* l) {
    __builtin_amdgcn_global_load_lds((const __attribute__((address_space(1))) void*)g,
                                     (__attribute__((address_space(3))) void*)l,
                                     16, 0, 0);
}

// ------------------------------- fused setup (one launch) --------------------
// [0,2560): transposes {te_w1->tw1t, mlp_w1->w1t, mlp_w2->w2t} f32->bf16 [Npad x 1024]
// [2560,2784): pjb  = bf16(proj_w)  [448 x 1024], rows >= 400 zero
// [2784,3296): tw2b = bf16(te_w2)   [1024 x 1024] (no transpose)
// [3296,7296): E0 bf16 timestep-embedding table (1000x1024)
// [7296,7300): colconst[j] = te_b2[j]+proj_b[j]+L30F*sum proj_w[16:400][j]; zbias=0
// 7300: schedules + per-t loss table + acc/counter zero
__global__ __launch_bounds__(256) void setup_all(
    const float* __restrict__ te_w1, const float* __restrict__ mlp_w1,
    const float* __restrict__ mlp_w2, const float* __restrict__ te_w2,
    __hip_bfloat16* __restrict__ tw1t, __hip_bfloat16* __restrict__ w1t,
    __hip_bfloat16* __restrict__ w2t,
    __hip_bfloat16* __restrict__ pjb, __hip_bfloat16* __restrict__ tw2b,
    __hip_bfloat16* __restrict__ E0, const float* __restrict__ proj_w,
    const float* __restrict__ proj_b, const float* __restrict__ te_b2,
    float* __restrict__ colconst, float* __restrict__ zbias,
    float* __restrict__ sched, float* __restrict__ ltbl,
    double* __restrict__ acc) {
    const int bid = blockIdx.x, tid = threadIdx.x;
    if (bid < 2560) {
        // transpose: W[K x Nw] f32 -> Wt[Npad x 1024] bf16 (zero pad)
        const int boff[4] = {0, 1024, 2048, 2560};
        const int nxs[3]  = {32, 32, 16};
        const int Nws[3]  = {1024, 1024, 400};
        const int Nps[3]  = {1024, 1024, 512};
        int job = 0;
#pragma unroll
        for (int j = 1; j < 3; ++j) job += (bid >= boff[j]) ? 1 : 0;
        const float* W = (job == 0) ? te_w1 : (job == 1) ? mlp_w1 : mlp_w2;
        __hip_bfloat16* Wt = (job == 0) ? tw1t : (job == 1) ? w1t : w2t;
        const int lb = bid - boff[job];
        const int Nw = Nws[job], Npad = Nps[job];
        const int n0 = (lb % nxs[job]) * 32, k0 = (lb / nxs[job]) * 32;
        __shared__ float t[32][33];
        int c = tid & 31, r8 = tid >> 5;
#pragma unroll
        for (int i = 0; i < 32; i += 8) {
            int k = k0 + r8 + i, n = n0 + c;
            t[r8 + i][c] = (n < Nw) ? W[(size_t)k * Nw + n] : 0.0f;
        }
        __syncthreads();
#pragma unroll
        for (int i = 0; i < 32; i += 8) {
            int n = n0 + r8 + i, k = k0 + c;
            if (n < Npad) Wt[(size_t)n * 1024 + k] = __float2bfloat16(t[c][r8 + i]);
        }
    } else if (bid < 2784) {
        int idx = (bid - 2560) * 2048 + tid * 8;
        int r = idx >> 10;
        __hip_bfloat16 v[8];
        if (r < 400) {
            const float* src = proj_w + idx;
#pragma unroll
            for (int q = 0; q < 8; ++q) v[q] = __float2bfloat16(src[q]);
        } else {
#pragma unroll
            for (int q = 0; q < 8; ++q) v[q] = __float2bfloat16(0.0f);
        }
        *(short8*)(pjb + idx) = *(const short8*)v;
    } else if (bid < 3296) {
        int idx = (bid - 2784) * 2048 + tid * 8;
        const float* src = te_w2 + idx;
        __hip_bfloat16 v[8];
#pragma unroll
        for (int q = 0; q < 8; ++q) v[q] = __float2bfloat16(src[q]);
        *(short8*)(tw2b + idx) = *(const short8*)v;
    } else if (bid < 7296) {
        int gid = (bid - 3296) * 256 + tid;
        int t = gid >> 10, j = gid & 1023;
        int jj = (j < 512) ? j : j - 512;
        float freq = expf(-logf(10000.0f) * (float)jj / 512.0f);
        float arg = (float)t * freq;
        E0[gid] = __float2bfloat16((j < 512) ? cosf(arg) : sinf(arg));
    } else if (bid < 7300) {
        int j = (bid - 7296) * 256 + tid;
        float s = 0.0f;
        for (int r = 16; r < 400; ++r) s += proj_w[(size_t)r * 1024 + j];
        colconst[j] = te_b2[j] + proj_b[j] + L30F * s;
        zbias[j] = 0.0f;
    } else {
        __shared__ double la_s[1000];
        __shared__ double lca_s[1000];
        const double PI = 3.14159265358979323846;
        for (int i = tid; i < 1000; i += 256) {
            double u0 = ((double)i / 1000.0 + 0.008) / 1.008 * PI * 0.5;
            double u1 = ((double)(i + 1) / 1000.0 + 0.008) / 1.008 * PI * 0.5;
            double c0 = cos(u0), c1 = cos(u1);
            double beta = 1.0 - (c1 * c1) / (c0 * c0);
            if (beta > 0.999) beta = 0.999;
            la_s[i] = log(1.0 - beta);
        }
        __syncthreads();
        if (tid == 0) {
            double run = 0.0;
            for (int i = 0; i < 1000; ++i) { run += la_s[i]; lca_s[i] = run; }
            *acc = 0.0;
            *((int*)(acc + 1)) = 0;   // completion counter for loss finalize
        }
        __syncthreads();
        for (int i = tid; i < 1000; i += 256) {
            double la = la_s[i], lca = lca_s[i];
            sched[i]        = (float)la;
            sched[1000 + i] = (float)log(1.0 - exp(la) + 1e-40);
            sched[2000 + i] = (float)lca;
            sched[3000 + i] = (float)log(1.0 - exp(lca) + 1e-40);
            sched[4000 + i] = (float)sqrt(exp(lca));
            sched[5000 + i] = (float)sqrt(1.0 - exp(lca));
            // per-t loss table: {A1, B1, B1p, Qh, Qo, C0 (xc!=s), C1 (xc==s), 0}
            double alpha = exp(la);
            double A1, B1;
            if (i == 0) { A1 = 1.0; B1 = 0.0; }
            else { double ab = exp(lca_s[i - 1]); A1 = ab; B1 = (1.0 - ab) / 16.0; }
            double B1p = 1e-30 * A1 + B1;
            double Qh = alpha + (1.0 - alpha) / 16.0;
            double Qo = 1e-30 * alpha + (1.0 - alpha) / 16.0;
            double C0 = 0.0, C1 = 0.0;
            if (i > 0) {
                double UTh1 = (A1 + B1) * Qh, UTo = B1p * Qo, UTs = B1p * Qh;
                double ST1 = UTh1 + 15.0 * UTo;
                double p1 = UTh1 / ST1, p0 = UTo / ST1;
                C1 = p1 * log(p1) + 15.0 * p0 * log(p0);
                double UTh0 = (A1 + B1) * Qo;
                double ST0 = UTh0 + UTs + 14.0 * UTo;
                double pxc = UTh0 / ST0, ps = UTs / ST0, po = UTo / ST0;
                C0 = pxc * log(pxc) + ps * log(ps) + 14.0 * po * log(po);
            }
            ltbl[i * 8 + 0] = (float)A1;
            ltbl[i * 8 + 1] = (float)B1;
            ltbl[i * 8 + 2] = (float)B1p;
            ltbl[i * 8 + 3] = (float)Qh;
            ltbl[i * 8 + 4] = (float)Qo;
            ltbl[i * 8 + 5] = (float)C0;
            ltbl[i * 8 + 6] = (float)C1;
            ltbl[i * 8 + 7] = 0.0f;
        }
    }
}

// ------------------ runtime-epi 64-tile GEMM body (used by mid_all) ----------
// C[M,Nreal] = (silu?)(A @ Bt^T + bias), bf16 out. BK=32, 4 waves 2x2, 2x2 frags.
__device__ __forceinline__ void gemm64_body(
    bool silu, const __hip_bfloat16* A, const __hip_bfloat16* Bt,
    const float* bias, __hip_bfloat16* C, int M, int Kd, int Nreal,
    int Cstride, int mb, int nb, char* smem, int tid) {
    __hip_bfloat16* As = (__hip_bfloat16*)smem;
    __hip_bfloat16* Bs = As + 64 * 32;
    const int lane = tid & 63, wave = tid >> 6;
    const int wm = wave >> 1, wn = wave & 1;
    const int m0 = mb * 64, n0 = nb * 64;

    const __hip_bfloat16* gsrc[2];
    char* ldst[2];
#pragma unroll
    for (int ii = 0; ii < 2; ++ii) {
        int gc = wave * 2 + ii;
        int mat = gc >> 2, rem = gc & 3;
        int row = rem * 16 + (lane >> 2);
        int col = (lane & 3) * 8;
        if (mat == 0) {
            int r = m0 + row; if (r > M - 1) r = M - 1;
            gsrc[ii] = A + (size_t)r * Kd + col;
            ldst[ii] = (char*)As + rem * 1024;
        } else {
            int r = n0 + row;
            gsrc[ii] = Bt + (size_t)r * Kd + col;
            ldst[ii] = (char*)Bs + rem * 1024;
        }
    }
    f32x4 acc[2][2] = {};
    const int q8 = (lane >> 4) * 8;
    const int l15 = lane & 15;
    for (int k0 = 0; k0 < Kd; k0 += 32) {
        glds16(gsrc[0] + k0, ldst[0]);
        glds16(gsrc[1] + k0, ldst[1]);
        __syncthreads();
        short8 af[2], bfr[2];
#pragma unroll
        for (int i = 0; i < 2; ++i) {
            af[i]  = *(const short8*)(As + (size_t)(wm * 32 + i * 16 + l15) * 32 + q8);
            bfr[i] = *(const short8*)(Bs + (size_t)(wn * 32 + i * 16 + l15) * 32 + q8);
        }
#pragma unroll
        for (int i = 0; i < 2; ++i)
#pragma unroll
            for (int j = 0; j < 2; ++j)
                acc[i][j] = __builtin_amdgcn_mfma_f32_16x16x32_bf16(
                    af[i], bfr[j], acc[i][j], 0, 0, 0);
        __syncthreads();
    }
#pragma unroll
    for (int i = 0; i < 2; ++i) {
        int mbase = m0 + wm * 32 + i * 16 + (lane >> 4) * 4;
#pragma unroll
        for (int j = 0; j < 2; ++j) {
            int n = n0 + wn * 32 + j * 16 + l15;
            if (n >= Nreal) continue;
            float bv = bias[n];
#pragma unroll
            for (int r = 0; r < 4; ++r) {
                int m = mbase + r;
                if (m >= M) continue;
                float v = acc[i][j][r] + bv;
                if (silu) v = v / (1.0f + expf(-v));
                C[(size_t)m * Cstride + n] = __float2bfloat16(v);
            }
        }
    }
}

// ------------------- mid: prep_x + PWT + E1 + W12t + bias2 (one launch) ------
// [0,1024): prep_x   [1024,1136): PWT   [1136,1392): E1   [1392,1648): W12t
// [1648,1652): bias2[k] = sum_j colconst[j]*mlp_w1[j][k] + mlp_b1[k]
__global__ __launch_bounds__(256) void mid_all(
    const float* __restrict__ x_num, const int* __restrict__ x_cat,
    const int* __restrict__ t_in, const float* __restrict__ noise,
    const float* __restrict__ gum, const float* __restrict__ sched,
    __hip_bfloat16* __restrict__ X, int* __restrict__ hot,
    const __hip_bfloat16* __restrict__ w1t, const __hip_bfloat16* __restrict__ pjb,
    const __hip_bfloat16* __restrict__ tw2b, const __hip_bfloat16* __restrict__ E0,
    const __hip_bfloat16* __restrict__ tw1t,
    const float* __restrict__ te_b1, const float* __restrict__ zbias,
    __hip_bfloat16* __restrict__ PWT, __hip_bfloat16* __restrict__ E1,
    __hip_bfloat16* __restrict__ W12t,
    const float* __restrict__ colconst, const float* __restrict__ mlp_w1,
    const float* __restrict__ mlp_b1, float* __restrict__ bias2) {
    __shared__ __align__(16) char SM[8192];
    const int bid = blockIdx.x, tid = threadIdx.x;
    if (bid < 1024) {
        // ---- prep_x: gumbel argmax + build X[B x 416] bf16
        float* xnt = (float*)SM;                    // [16][16]
        int* sh_hot = (int*)(SM + 1024);            // [16][24]
        int* sh_t = (int*)(SM + 1024 + 1536);       // [16]
        const int b0 = bid * 16;
        const float* LOG_CA = sched + 2000;
        const float* LOG_1M_CA = sched + 3000;
        const float* SQ_AC = sched + 4000;
        const float* SQ_1M = sched + 5000;
        if (tid < 16) sh_t[tid] = t_in[b0 + tid];
        __syncthreads();
        {
            int r = tid >> 4, i = tid & 15;
            int t = sh_t[r];
            xnt[r * 16 + i] = SQ_AC[t] * x_num[(size_t)(b0 + r) * 16 + i] +
                              SQ_1M[t] * noise[(size_t)(b0 + r) * 16 + i];
        }
        for (int task = tid; task < 16 * 24; task += 256) {
            int r = task / 24, c = task - r * 24;
            int t = sh_t[r];
            int xc = x_cat[(size_t)(b0 + r) * 24 + c];
            float l1 = LOG_1M_CA[t] - LOGKF;
            float lca = LOG_CA[t];
            float vh = lae(lca, l1);
            float vo = lae(L30F + lca, l1);
            const float* gu = gum + (size_t)(b0 + r) * 384 + c * 16;
            float best = -3.0e38f;
            int bi = 0;
#pragma unroll
            for (int k = 0; k < 16; ++k) {
                float g = -logf(-logf(gu[k] + 1e-30f) + 1e-30f);
                float v = g + ((k == xc) ? vh : vo);
                if (v > best) { best = v; bi = k; }
            }
            sh_hot[r * 24 + c] = bi;
            hot[(size_t)(b0 + r) * 24 + c] = bi;
        }
        __syncthreads();
        const float DELTA = 69.07755279f;  // -L30F
#pragma unroll
        for (int it = 0; it < 4; ++it) {
            int idx = it * 256 + tid;          // 16*52 = 832 short8 stores
            if (idx < 832) {
                int r = idx / 52, jc = idx - r * 52;
                int j0 = jc * 8;
                __hip_bfloat16 v[8];
#pragma unroll
                for (int qq = 0; qq < 8; ++qq) {
                    int j = j0 + qq;
                    float f = 0.0f;
                    if (j < 16) {
                        f = xnt[r * 16 + j];
                    } else if (j < 400) {
                        int c = (j - 16) >> 4, k = (j - 16) & 15;
                        f = (sh_hot[r * 24 + c] == k) ? DELTA : 0.0f;
                    }
                    v[qq] = __float2bfloat16(f);
                }
                *(short8*)(X + (size_t)(b0 + r) * 416 + j0) = *(const short8*)v;
            }
        }
    } else if (bid < 1136) {
        // ---- PWT[j,k] = sum_n w1[n,j] proj_w[k,n] -> [1024 x 416]
        int lb = bid - 1024;
        gemm64_body(false, w1t, pjb, zbias, PWT, 1024, 1024, 416, 416,
                    lb / 7, lb % 7, SM, tid);
    } else if (bid < 1392) {
        // ---- E1 = silu(E0 @ te_w1 + te_b1)  [1000 x 1024]
        int lb = bid - 1136;
        gemm64_body(true, E0, tw1t, te_b1, E1, 1000, 1024, 1024, 1024,
                    lb >> 4, lb & 15, SM, tid);
    } else if (bid < 1648) {
        // ---- W12t[k,n] = sum_j w1[j,k] te_w2[n,j]  ( = (te_w2@w1)^T )
        int lb = bid - 1392;
        gemm64_body(false, w1t, tw2b, zbias, W12t, 1024, 1024, 1024, 1024,
                    lb >> 4, lb & 15, SM, tid);
    } else {
        // ---- bias2 (f32): all h-space constants projected through w1
        int k = (bid - 1648) * 256 + tid;
        float s = mlp_b1[k];
        for (int j = 0; j < 1024; ++j)
            s += colconst[j] * mlp_w1[(size_t)j * 1024 + k];
        bias2[k] = s;
    }
}

// ------------------------------------------------------------ bf16 MFMA GEMM
// EPI: 5 = plain bf16 store,
// 6 = +embrow[t[m]][n] (bf16 table, LDS-gathered via batched glds16) + relu + bf16
//     (TILE==128 only),
// 4 = fused loss: acc -> LDS scoreboard -> per-(row,cat) linear-space loss,
//     last-block finalize writes Cout (float*). rowbias = per-t loss table.
template <int EPI, int TILE>
__global__ __launch_bounds__(256) void gemm_mfma(
    const __hip_bfloat16* __restrict__ A, const __hip_bfloat16* __restrict__ Bt,
    const float* __restrict__ bias, void* __restrict__ Cout,
    int M, int Kd, int Nreal, int Cstride,
    const int* __restrict__ tidx, const float* __restrict__ rowbias,
    const int* __restrict__ x_cat, const int* __restrict__ t_in,
    const int* __restrict__ hot, const float* __restrict__ noise,
    const float* __restrict__ sched, double* __restrict__ acc_out) {
    constexpr int FM  = TILE / 32;
    constexpr int CPM = TILE / 16;
    constexpr int CPW = TILE / 32;
    constexpr int STAGE = 4 * TILE * 32;
    constexpr int SCORE = TILE * TILE * 4;
    constexpr int SMEM_BYTES = (EPI == 4) ? (SCORE > STAGE ? SCORE : STAGE)
                               : (EPI == 6) ? (STAGE + TILE * TILE * 2)
                               : STAGE;
    __shared__ __align__(16) char SMEM[SMEM_BYTES];
    __hip_bfloat16* As = (__hip_bfloat16*)SMEM;
    __hip_bfloat16* Bs = As + TILE * 32;

    const int tid = threadIdx.x;
    const int lane = tid & 63, wave = tid >> 6;
    const int wm = wave >> 1, wn = wave & 1;

    // XCD swizzle (same-m n-blocks consecutive within one XCD)
    int mb, nb;
    {
        int nbx = gridDim.x, nby = gridDim.y;
        int b = blockIdx.y * nbx + blockIdx.x;
        if ((nby & 7) == 0) {
            int x = b & 7, g = b >> 3;
            nb = g % nbx;
            mb = x + 8 * (g / nbx);
        } else { mb = blockIdx.y; nb = blockIdx.x; }
    }
    const int m0 = mb * TILE, n0 = nb * TILE;

    const __hip_bfloat16* gsrc[CPW];
    char* ldst[CPW];
#pragma unroll
    for (int ii = 0; ii < CPW; ++ii) {
        int gc = wave * CPW + ii;
        int mat = gc / CPM, rem = gc % CPM;
        int row = rem * 16 + (lane >> 2);
        int col = (lane & 3) * 8;
        if (mat == 0) {
            int r = m0 + row; if (r > M - 1) r = M - 1;
            gsrc[ii] = A + (size_t)r * Kd + col;
            ldst[ii] = (char*)As + rem * 1024;
        } else {
            int r = n0 + row;
            gsrc[ii] = Bt + (size_t)r * Kd + col;
            ldst[ii] = (char*)Bs + rem * 1024;
        }
    }

    if (EPI == 6) {
        char* LE = SMEM + STAGE;
        const __hip_bfloat16* embp = (const __hip_bfloat16*)rowbias;
        int tvec = tidx[m0 + wave * 32 + (lane & 31)];
#pragma unroll
        for (int b = 0; b < 8; ++b) {
            int trow = __shfl(tvec, b * 4 + (lane >> 4));
            glds16((const char*)(embp + (size_t)trow * 1024 + n0) + (lane & 15) * 16,
                   LE + (wave * 32 + b * 4) * 256);
        }
    }

    f32x4 acc[FM][FM] = {};
    const int q8 = (lane >> 4) * 8;
    const int l15 = lane & 15;

    for (int k0 = 0; k0 < Kd; k0 += 32) {
#pragma unroll
        for (int ii = 0; ii < CPW; ++ii) glds16(gsrc[ii] + k0, ldst[ii]);
        __syncthreads();
        short8 af[FM], bfr[FM];
#pragma unroll
        for (int i = 0; i < FM; ++i) {
            af[i]  = *(const short8*)(As + (size_t)(wm * (TILE / 2) + i * 16 + l15) * 32 + q8);
            bfr[i] = *(const short8*)(Bs + (size_t)(wn * (TILE / 2) + i * 16 + l15) * 32 + q8);
        }
#pragma unroll
        for (int i = 0; i < FM; ++i)
#pragma unroll
            for (int j = 0; j < FM; ++j)
                acc[i][j] = __builtin_amdgcn_mfma_f32_16x16x32_bf16(
                    af[i], bfr[j], acc[i][j], 0, 0, 0);
        __syncthreads();
    }

    if (EPI == 4) {
        float* S = (float*)SMEM;
#pragma unroll
        for (int i = 0; i < FM; ++i) {
            int rbase = wm * (TILE / 2) + i * 16 + (lane >> 4) * 4;
#pragma unroll
            for (int j = 0; j < FM; ++j) {
                int lcol = wn * (TILE / 2) + j * 16 + l15;
#pragma unroll
                for (int r = 0; r < 4; ++r) {
                    int row = rbase + r;
                    S[row * TILE + ((lcol + row) & (TILE - 1))] = acc[i][j][r];
                }
            }
        }
        __syncthreads();

        double local = 0.0;
        const float* ltbl = rowbias;
        constexpr int PAIRS = TILE * (TILE / 16);
        for (int p = tid; p < PAIRS; p += 256) {
            int ml = p & (TILE - 1), cg = p / TILE;
            int colbase = n0 + cg * 16;
            if (colbase >= 400) continue;
            int m = m0 + ml;
            float ocv[16];
#pragma unroll
            for (int k = 0; k < 16; ++k)
                ocv[k] = S[ml * TILE + ((cg * 16 + k + ml) & (TILE - 1))] + bias[colbase + k];
            if (colbase == 0) {
#pragma unroll
                for (int k = 0; k < 16; ++k) {
                    float d = noise[(size_t)m * 16 + k] - ocv[k];
                    local += (double)(d * d) * (1.0 / (16.0 * BATCH));
                }
            } else {
                int c = (colbase - 16) >> 4;
                int t = t_in[m];
                int xc = x_cat[m * 24 + c];
                int s = hot[m * 24 + c];
                const float* tb = ltbl + t * 8;
                float A1 = tb[0], B1 = tb[1], B1p = tb[2], Qh = tb[3], Qo = tb[4];
                float mx = -3e38f;
#pragma unroll
                for (int k = 0; k < 16; ++k) mx = fmaxf(mx, ocv[k]);
                float E[16];
                float sm = 0.0f;
#pragma unroll
                for (int k = 0; k < 16; ++k) { E[k] = expf(ocv[k] - mx); sm += E[k]; }
                float A1s = A1 / sm;
                float SU = 0.0f, slU = 0.0f, lUxc = 0.0f, lUs = 0.0f;
#pragma unroll
                for (int k = 0; k < 16; ++k) {
                    float U = (E[k] * A1s + B1) * ((k == s) ? Qh : Qo);
                    SU += U;
                    float l = logf(fmaxf(U, 1e-37f));
                    slU += l;
                    if (k == xc) lUxc = l;
                    if (k == s)  lUs = l;
                }
                float lSU = logf(SU);
                float Wh, Ws, Wo, C;
                if (t == 0) {
                    Wh = 1.0f; Ws = 1e-30f; Wo = 1e-30f; C = 0.0f;
                } else {
                    int e = (xc == s);
                    float UTh = (A1 + B1) * (e ? Qh : Qo);
                    float UTs = B1p * Qh;
                    float UTo = B1p * Qo;
                    float ST = e ? (UTh + 15.0f * UTo) : (UTh + UTs + 14.0f * UTo);
                    float rST = 1.0f / ST;
                    Wh = UTh * rST; Wo = UTo * rST; Ws = UTs * rST;
                    C = e ? tb[6] : tb[5];
                }
                float wsTerm = (xc == s) ? 0.0f : (Ws - Wo);
                float SPU = Wo * slU + (Wh - Wo) * lUxc + wsTerm * lUs;
                float Lt = C - SPU + lSU;
                local += (double)Lt * (1.0 / (24.0 * BATCH));
            }
        }
        for (int off = 32; off > 0; off >>= 1)
            local += __shfl_down(local, off);
        __syncthreads();
        double* wred = (double*)SMEM;
        if (lane == 0) wred[wave] = local;
        __syncthreads();
        if (tid == 0) {
            atomicAdd(acc_out, wred[0] + wred[1] + wred[2] + wred[3]);
            __threadfence();
            int* counter = (int*)(acc_out + 1);
            int total = gridDim.x * gridDim.y;
            int prev = atomicAdd(counter, 1);
            if (prev == total - 1) {
                double sum = atomicAdd(acc_out, 0.0);
                float lcaT = sched[2999];
                float l1mT = sched[3999] - LOGKF;
                float ph = lae(lcaT, l1mT);
                float po = lae(L30F + lcaT, l1mT);
                float prior = expf(ph) * (ph + LOGKF) + 15.0f * expf(po) * (po + LOGKF);
                ((float*)Cout)[0] = (float)(sum + (double)prior);
            }
        }
        return;
    }

    const __hip_bfloat16* LE = (const __hip_bfloat16*)(SMEM + STAGE);
#pragma unroll
    for (int i = 0; i < FM; ++i) {
        int mlbase = wm * (TILE / 2) + i * 16 + (lane >> 4) * 4;
#pragma unroll
        for (int j = 0; j < FM; ++j) {
            int nl = wn * (TILE / 2) + j * 16 + l15;
            int n = n0 + nl;
            if (n >= Nreal) continue;
            float bv = bias[n];
#pragma unroll
            for (int r = 0; r < 4; ++r) {
                int ml = mlbase + r;
                int m = m0 + ml;
                if (m >= M) continue;
                float v = acc[i][j][r] + bv;
                if (EPI == 6) { v += __bfloat162float(LE[ml * TILE + nl]); v = fmaxf(v, 0.0f); }
                ((__hip_bfloat16*)Cout)[(size_t)m * Cstride + n] = __float2bfloat16(v);
            }
        }
    }
}

extern "C" void kernel_launch(void* const* d_in, const int* in_sizes, int n_in,
                              void* d_out, int out_size, void* d_ws, size_t ws_size,
                              hipStream_t stream) {
    const float* x_num  = (const float*)d_in[0];
    const int*   x_cat  = (const int*)d_in[1];
    const int*   t_in   = (const int*)d_in[2];
    const float* noise  = (const float*)d_in[3];
    const float* gum    = (const float*)d_in[4];
    const float* te_w1  = (const float*)d_in[5];
    const float* te_b1  = (const float*)d_in[6];
    const float* te_w2  = (const float*)d_in[7];
    const float* te_b2  = (const float*)d_in[8];
    const float* proj_w = (const float*)d_in[9];
    const float* proj_b = (const float*)d_in[10];
    const float* mlp_w1 = (const float*)d_in[11];
    const float* mlp_b1 = (const float*)d_in[12];
    const float* mlp_w2 = (const float*)d_in[13];
    const float* mlp_b2 = (const float*)d_in[14];
    float* out = (float*)d_out;

    char* w = (char*)d_ws;
    size_t off = 0;
    auto alloc = [&](size_t bytes) {
        void* p = w + off;
        off += (bytes + 1023) & ~(size_t)1023;
        return p;
    };
    double* acc     = (double*)alloc(1024);       // acc[0]=sum, acc[1] (as int)=counter
    float* sched    = (float*)alloc(6 * 1000 * 4);
    float* ltbl     = (float*)alloc(8 * 1000 * 4);
    int*   hot      = (int*)alloc((size_t)BATCH * 24 * 4);
    float* colconst = (float*)alloc(1024 * 4);
    float* zbias    = (float*)alloc(1024 * 4);
    float* bias2    = (float*)alloc(1024 * 4);
    __hip_bfloat16* E0    = (__hip_bfloat16*)alloc((size_t)1024 * 1024 * 2);
    __hip_bfloat16* E1    = (__hip_bfloat16*)alloc((size_t)1024 * 1024 * 2);
    __hip_bfloat16* EMB2  = (__hip_bfloat16*)alloc((size_t)1024 * 1024 * 2);
    __hip_bfloat16* tw1t  = (__hip_bfloat16*)alloc((size_t)1024 * 1024 * 2);
    __hip_bfloat16* tw2b  = (__hip_bfloat16*)alloc((size_t)1024 * 1024 * 2);
    __hip_bfloat16* W12t  = (__hip_bfloat16*)alloc((size_t)1024 * 1024 * 2);
    __hip_bfloat16* w1t   = (__hip_bfloat16*)alloc((size_t)1024 * 1024 * 2);
    __hip_bfloat16* w2t   = (__hip_bfloat16*)alloc((size_t)512 * 1024 * 2);
    __hip_bfloat16* pjb   = (__hip_bfloat16*)alloc((size_t)448 * 1024 * 2);
    __hip_bfloat16* PWT   = (__hip_bfloat16*)alloc((size_t)1024 * 416 * 2);
    __hip_bfloat16* X     = (__hip_bfloat16*)alloc((size_t)BATCH * 416 * 2);
    __hip_bfloat16* R     = (__hip_bfloat16*)alloc((size_t)BATCH * 1024 * 2);

    // 1) setup: transposes + casts + E0 + colconst + schedules/ltbl + acc zero
    setup_all<<<7301, 256, 0, stream>>>(te_w1, mlp_w1, mlp_w2, te_w2,
                                        tw1t, w1t, w2t, pjb, tw2b,
                                        E0, proj_w, proj_b, te_b2,
                                        colconst, zbias, sched, ltbl, acc);
    // 2) mid: prep_x + PWT + E1 + W12t + bias2
    mid_all<<<1652, 256, 0, stream>>>(x_num, x_cat, t_in, noise, gum, sched, X, hot,
                                      w1t, pjb, tw2b, E0, tw1t, te_b1, zbias,
                                      PWT, E1, W12t, colconst, mlp_w1, mlp_b1, bias2);
    // 3) EMB2 = E1 @ W12t^T + bias2   [per-t hidden-layer bias table]
    gemm_mfma<5, 64><<<dim3(16, 16), 256, 0, stream>>>(
        E1, W12t, bias2, EMB2, 1000, 1024, 1024, 1024,
        nullptr, nullptr, nullptr, nullptr, nullptr, nullptr, nullptr, nullptr);
    // 4) R = relu(X @ PWT^T + EMB2[t])
    gemm_mfma<6, 128><<<dim3(8, 128), 256, 0, stream>>>(
        X, PWT, zbias, R, BATCH, 416, 1024, 1024,
        t_in, (const float*)EMB2, nullptr, nullptr, nullptr, nullptr, nullptr, nullptr);
    // 5) loss: (R @ mlp_w2 + mlp_b2) -> scoreboard -> linear-space loss -> out
    gemm_mfma<4, 64><<<dim3(7, 256), 256, 0, stream>>>(
        R, w2t, mlp_b2, out, BATCH, 1024, 400, 0,
        nullptr, ltbl, x_cat, t_in, hot, noise, sched, acc);
}

// Round 13
// 257.338 us; speedup vs baseline: 1.1862x; 1.1862x over previous
//
#include <hip/hip_runtime.h>
#include <hip/hip_bf16.h>
#include <math.h>

#define BATCH 16384
#define NCAT 24

// log(1e-30f), log(16)
#define L30F  (-69.07755279f)
#define LOGKF (2.7725887f)

typedef __attribute__((ext_vector_type(8))) short short8;
typedef __attribute__((ext_vector_type(4))) float f32x4;

__device__ __forceinline__ float lae(float a, float b) {
    float m = fmaxf(a, b);
    return m + logf(expf(a - m) + expf(b - m));
}

__device__ __forceinline__ void glds16(const void* g, void* l) {
    __builtin_amdgcn_global_load_lds((const __attribute__((address_space(1))) void*)g,
                                     (__attribute__((address_space(3))) void*)l,
                                     16, 0, 0);
}

// ------------------------------- fused setup (one launch) --------------------
// [0,2560): transposes {te_w1->tw1t, mlp_w1->w1t, mlp_w2->w2t} f32->bf16 [Npad x 1024]
// [2560,2784): pjb  = bf16(proj_w)  [448 x 1024], rows >= 400 zero
// [2784,3296): tw2b = bf16(te_w2)   [1024 x 1024] (no transpose)
// [3296,7296): E0 bf16 timestep-embedding table (1000x1024)
// [7296,7300): colconst[j] = te_b2[j]+proj_b[j]+L30F*sum proj_w[16:400][j]; zbias=0
// 7300: schedules + per-t loss table + acc zero
__global__ __launch_bounds__(256) void setup_all(
    const float* __restrict__ te_w1, const float* __restrict__ mlp_w1,
    const float* __restrict__ mlp_w2, const float* __restrict__ te_w2,
    __hip_bfloat16* __restrict__ tw1t, __hip_bfloat16* __restrict__ w1t,
    __hip_bfloat16* __restrict__ w2t,
    __hip_bfloat16* __restrict__ pjb, __hip_bfloat16* __restrict__ tw2b,
    __hip_bfloat16* __restrict__ E0, const float* __restrict__ proj_w,
    const float* __restrict__ proj_b, const float* __restrict__ te_b2,
    float* __restrict__ colconst, float* __restrict__ zbias,
    float* __restrict__ sched, float* __restrict__ ltbl,
    double* __restrict__ acc) {
    const int bid = blockIdx.x, tid = threadIdx.x;
    if (bid < 2560) {
        // transpose: W[K x Nw] f32 -> Wt[Npad x 1024] bf16 (zero pad)
        const int boff[4] = {0, 1024, 2048, 2560};
        const int nxs[3]  = {32, 32, 16};
        const int Nws[3]  = {1024, 1024, 400};
        const int Nps[3]  = {1024, 1024, 512};
        int job = 0;
#pragma unroll
        for (int j = 1; j < 3; ++j) job += (bid >= boff[j]) ? 1 : 0;
        const float* W = (job == 0) ? te_w1 : (job == 1) ? mlp_w1 : mlp_w2;
        __hip_bfloat16* Wt = (job == 0) ? tw1t : (job == 1) ? w1t : w2t;
        const int lb = bid - boff[job];
        const int Nw = Nws[job], Npad = Nps[job];
        const int n0 = (lb % nxs[job]) * 32, k0 = (lb / nxs[job]) * 32;
        __shared__ float t[32][33];
        int c = tid & 31, r8 = tid >> 5;
#pragma unroll
        for (int i = 0; i < 32; i += 8) {
            int k = k0 + r8 + i, n = n0 + c;
            t[r8 + i][c] = (n < Nw) ? W[(size_t)k * Nw + n] : 0.0f;
        }
        __syncthreads();
#pragma unroll
        for (int i = 0; i < 32; i += 8) {
            int n = n0 + r8 + i, k = k0 + c;
            if (n < Npad) Wt[(size_t)n * 1024 + k] = __float2bfloat16(t[c][r8 + i]);
        }
    } else if (bid < 2784) {
        int idx = (bid - 2560) * 2048 + tid * 8;
        int r = idx >> 10;
        __hip_bfloat16 v[8];
        if (r < 400) {
            const float* src = proj_w + idx;
#pragma unroll
            for (int q = 0; q < 8; ++q) v[q] = __float2bfloat16(src[q]);
        } else {
#pragma unroll
            for (int q = 0; q < 8; ++q) v[q] = __float2bfloat16(0.0f);
        }
        *(short8*)(pjb + idx) = *(const short8*)v;
    } else if (bid < 3296) {
        int idx = (bid - 2784) * 2048 + tid * 8;
        const float* src = te_w2 + idx;
        __hip_bfloat16 v[8];
#pragma unroll
        for (int q = 0; q < 8; ++q) v[q] = __float2bfloat16(src[q]);
        *(short8*)(tw2b + idx) = *(const short8*)v;
    } else if (bid < 7296) {
        int gid = (bid - 3296) * 256 + tid;
        int t = gid >> 10, j = gid & 1023;
        int jj = (j < 512) ? j : j - 512;
        float freq = expf(-logf(10000.0f) * (float)jj / 512.0f);
        float arg = (float)t * freq;
        E0[gid] = __float2bfloat16((j < 512) ? cosf(arg) : sinf(arg));
    } else if (bid < 7300) {
        int j = (bid - 7296) * 256 + tid;
        float s = 0.0f;
        for (int r = 16; r < 400; ++r) s += proj_w[(size_t)r * 1024 + j];
        colconst[j] = te_b2[j] + proj_b[j] + L30F * s;
        zbias[j] = 0.0f;
    } else {
        __shared__ double la_s[1000];
        __shared__ double lca_s[1000];
        const double PI = 3.14159265358979323846;
        for (int i = tid; i < 1000; i += 256) {
            double u0 = ((double)i / 1000.0 + 0.008) / 1.008 * PI * 0.5;
            double u1 = ((double)(i + 1) / 1000.0 + 0.008) / 1.008 * PI * 0.5;
            double c0 = cos(u0), c1 = cos(u1);
            double beta = 1.0 - (c1 * c1) / (c0 * c0);
            if (beta > 0.999) beta = 0.999;
            la_s[i] = log(1.0 - beta);
        }
        __syncthreads();
        if (tid == 0) {
            double run = 0.0;
            for (int i = 0; i < 1000; ++i) { run += la_s[i]; lca_s[i] = run; }
            *acc = 0.0;
        }
        __syncthreads();
        for (int i = tid; i < 1000; i += 256) {
            double la = la_s[i], lca = lca_s[i];
            sched[i]        = (float)la;
            sched[1000 + i] = (float)log(1.0 - exp(la) + 1e-40);
            sched[2000 + i] = (float)lca;
            sched[3000 + i] = (float)log(1.0 - exp(lca) + 1e-40);
            sched[4000 + i] = (float)sqrt(exp(lca));
            sched[5000 + i] = (float)sqrt(1.0 - exp(lca));
            // per-t loss table: {A1, B1, B1p, Qh, Qo, C0 (xc!=s), C1 (xc==s), 0}
            double alpha = exp(la);
            double A1, B1;
            if (i == 0) { A1 = 1.0; B1 = 0.0; }
            else { double ab = exp(lca_s[i - 1]); A1 = ab; B1 = (1.0 - ab) / 16.0; }
            double B1p = 1e-30 * A1 + B1;
            double Qh = alpha + (1.0 - alpha) / 16.0;
            double Qo = 1e-30 * alpha + (1.0 - alpha) / 16.0;
            double C0 = 0.0, C1 = 0.0;
            if (i > 0) {
                double UTh1 = (A1 + B1) * Qh, UTo = B1p * Qo, UTs = B1p * Qh;
                double ST1 = UTh1 + 15.0 * UTo;
                double p1 = UTh1 / ST1, p0 = UTo / ST1;
                C1 = p1 * log(p1) + 15.0 * p0 * log(p0);
                double UTh0 = (A1 + B1) * Qo;
                double ST0 = UTh0 + UTs + 14.0 * UTo;
                double pxc = UTh0 / ST0, ps = UTs / ST0, po = UTo / ST0;
                C0 = pxc * log(pxc) + ps * log(ps) + 14.0 * po * log(po);
            }
            ltbl[i * 8 + 0] = (float)A1;
            ltbl[i * 8 + 1] = (float)B1;
            ltbl[i * 8 + 2] = (float)B1p;
            ltbl[i * 8 + 3] = (float)Qh;
            ltbl[i * 8 + 4] = (float)Qo;
            ltbl[i * 8 + 5] = (float)C0;
            ltbl[i * 8 + 6] = (float)C1;
            ltbl[i * 8 + 7] = 0.0f;
        }
    }
}

// ------------------ runtime-epi 64-tile GEMM body (used by mid_all) ----------
// C[M,Nreal] = (silu?)(A @ Bt^T + bias), bf16 out. BK=32, 4 waves 2x2, 2x2 frags.
__device__ __forceinline__ void gemm64_body(
    bool silu, const __hip_bfloat16* A, const __hip_bfloat16* Bt,
    const float* bias, __hip_bfloat16* C, int M, int Kd, int Nreal,
    int Cstride, int mb, int nb, char* smem, int tid) {
    __hip_bfloat16* As = (__hip_bfloat16*)smem;
    __hip_bfloat16* Bs = As + 64 * 32;
    const int lane = tid & 63, wave = tid >> 6;
    const int wm = wave >> 1, wn = wave & 1;
    const int m0 = mb * 64, n0 = nb * 64;

    const __hip_bfloat16* gsrc[2];
    char* ldst[2];
#pragma unroll
    for (int ii = 0; ii < 2; ++ii) {
        int gc = wave * 2 + ii;
        int mat = gc >> 2, rem = gc & 3;
        int row = rem * 16 + (lane >> 2);
        int col = (lane & 3) * 8;
        if (mat == 0) {
            int r = m0 + row; if (r > M - 1) r = M - 1;
            gsrc[ii] = A + (size_t)r * Kd + col;
            ldst[ii] = (char*)As + rem * 1024;
        } else {
            int r = n0 + row;
            gsrc[ii] = Bt + (size_t)r * Kd + col;
            ldst[ii] = (char*)Bs + rem * 1024;
        }
    }
    f32x4 acc[2][2] = {};
    const int q8 = (lane >> 4) * 8;
    const int l15 = lane & 15;
    for (int k0 = 0; k0 < Kd; k0 += 32) {
        glds16(gsrc[0] + k0, ldst[0]);
        glds16(gsrc[1] + k0, ldst[1]);
        __syncthreads();
        short8 af[2], bfr[2];
#pragma unroll
        for (int i = 0; i < 2; ++i) {
            af[i]  = *(const short8*)(As + (size_t)(wm * 32 + i * 16 + l15) * 32 + q8);
            bfr[i] = *(const short8*)(Bs + (size_t)(wn * 32 + i * 16 + l15) * 32 + q8);
        }
#pragma unroll
        for (int i = 0; i < 2; ++i)
#pragma unroll
            for (int j = 0; j < 2; ++j)
                acc[i][j] = __builtin_amdgcn_mfma_f32_16x16x32_bf16(
                    af[i], bfr[j], acc[i][j], 0, 0, 0);
        __syncthreads();
    }
#pragma unroll
    for (int i = 0; i < 2; ++i) {
        int mbase = m0 + wm * 32 + i * 16 + (lane >> 4) * 4;
#pragma unroll
        for (int j = 0; j < 2; ++j) {
            int n = n0 + wn * 32 + j * 16 + l15;
            if (n >= Nreal) continue;
            float bv = bias[n];
#pragma unroll
            for (int r = 0; r < 4; ++r) {
                int m = mbase + r;
                if (m >= M) continue;
                float v = acc[i][j][r] + bv;
                if (silu) v = v / (1.0f + expf(-v));
                C[(size_t)m * Cstride + n] = __float2bfloat16(v);
            }
        }
    }
}

// ------------------- mid: bias2 + PWT + E1 + W12t + prep_x (one launch) ------
// [0,16): bias2[k] = dot(w1t_row_k, colconst) + mlp_b1[k]   (64 k's per block)
// [16,128): PWT   [128,384): E1   [384,640): W12t   [640,1664): prep_x
__global__ __launch_bounds__(256) void mid_all(
    const float* __restrict__ x_num, const int* __restrict__ x_cat,
    const int* __restrict__ t_in, const float* __restrict__ noise,
    const float* __restrict__ gum, const float* __restrict__ sched,
    __hip_bfloat16* __restrict__ X, int* __restrict__ hot,
    const __hip_bfloat16* __restrict__ w1t, const __hip_bfloat16* __restrict__ pjb,
    const __hip_bfloat16* __restrict__ tw2b, const __hip_bfloat16* __restrict__ E0,
    const __hip_bfloat16* __restrict__ tw1t,
    const float* __restrict__ te_b1, const float* __restrict__ zbias,
    __hip_bfloat16* __restrict__ PWT, __hip_bfloat16* __restrict__ E1,
    __hip_bfloat16* __restrict__ W12t,
    const float* __restrict__ colconst, const float* __restrict__ mlp_b1,
    float* __restrict__ bias2) {
    __shared__ __align__(16) char SM[8192];
    const int bid = blockIdx.x, tid = threadIdx.x;
    if (bid < 16) {
        // ---- bias2: per wave, 16 k's; per k: 64-lane dot over 1024 elements
        const int lane = tid & 63, wave = tid >> 6;
        for (int kk = 0; kk < 16; ++kk) {
            int k = bid * 64 + wave * 16 + kk;
            const __hip_bfloat16* row = w1t + (size_t)k * 1024 + lane * 16;
            const float* cc = colconst + lane * 16;
            float s = 0.0f;
#pragma unroll
            for (int q = 0; q < 16; ++q)
                s = fmaf(__bfloat162float(row[q]), cc[q], s);
            for (int off = 32; off > 0; off >>= 1)
                s += __shfl_down(s, off);
            if (lane == 0) bias2[k] = s + mlp_b1[k];
        }
    } else if (bid < 128) {
        // ---- PWT[j,k] = sum_n w1[n,j] proj_w[k,n] -> [1024 x 416]
        int lb = bid - 16;
        gemm64_body(false, w1t, pjb, zbias, PWT, 1024, 1024, 416, 416,
                    lb / 7, lb % 7, SM, tid);
    } else if (bid < 384) {
        // ---- E1 = silu(E0 @ te_w1 + te_b1)  [1000 x 1024]
        int lb = bid - 128;
        gemm64_body(true, E0, tw1t, te_b1, E1, 1000, 1024, 1024, 1024,
                    lb >> 4, lb & 15, SM, tid);
    } else if (bid < 640) {
        // ---- W12t[k,n] = sum_j w1[j,k] te_w2[n,j]  ( = (te_w2@w1)^T )
        int lb = bid - 384;
        gemm64_body(false, w1t, tw2b, zbias, W12t, 1024, 1024, 1024, 1024,
                    lb >> 4, lb & 15, SM, tid);
    } else {
        // ---- prep_x: gumbel argmax + build X[B x 416] bf16
        float* xnt = (float*)SM;                    // [16][16]
        int* sh_hot = (int*)(SM + 1024);            // [16][24]
        int* sh_t = (int*)(SM + 1024 + 1536);       // [16]
        const int b0 = (bid - 640) * 16;
        const float* LOG_CA = sched + 2000;
        const float* LOG_1M_CA = sched + 3000;
        const float* SQ_AC = sched + 4000;
        const float* SQ_1M = sched + 5000;
        if (tid < 16) sh_t[tid] = t_in[b0 + tid];
        __syncthreads();
        {
            int r = tid >> 4, i = tid & 15;
            int t = sh_t[r];
            xnt[r * 16 + i] = SQ_AC[t] * x_num[(size_t)(b0 + r) * 16 + i] +
                              SQ_1M[t] * noise[(size_t)(b0 + r) * 16 + i];
        }
        for (int task = tid; task < 16 * 24; task += 256) {
            int r = task / 24, c = task - r * 24;
            int t = sh_t[r];
            int xc = x_cat[(size_t)(b0 + r) * 24 + c];
            float l1 = LOG_1M_CA[t] - LOGKF;
            float lca = LOG_CA[t];
            float vh = lae(lca, l1);
            float vo = lae(L30F + lca, l1);
            const float* gu = gum + (size_t)(b0 + r) * 384 + c * 16;
            float best = -3.0e38f;
            int bi = 0;
#pragma unroll
            for (int k = 0; k < 16; ++k) {
                float g = -logf(-logf(gu[k] + 1e-30f) + 1e-30f);
                float v = g + ((k == xc) ? vh : vo);
                if (v > best) { best = v; bi = k; }
            }
            sh_hot[r * 24 + c] = bi;
            hot[(size_t)(b0 + r) * 24 + c] = bi;
        }
        __syncthreads();
        const float DELTA = 69.07755279f;  // -L30F
#pragma unroll
        for (int it = 0; it < 4; ++it) {
            int idx = it * 256 + tid;          // 16*52 = 832 short8 stores
            if (idx < 832) {
                int r = idx / 52, jc = idx - r * 52;
                int j0 = jc * 8;
                __hip_bfloat16 v[8];
#pragma unroll
                for (int qq = 0; qq < 8; ++qq) {
                    int j = j0 + qq;
                    float f = 0.0f;
                    if (j < 16) {
                        f = xnt[r * 16 + j];
                    } else if (j < 400) {
                        int c = (j - 16) >> 4, k = (j - 16) & 15;
                        f = (sh_hot[r * 24 + c] == k) ? DELTA : 0.0f;
                    }
                    v[qq] = __float2bfloat16(f);
                }
                *(short8*)(X + (size_t)(b0 + r) * 416 + j0) = *(const short8*)v;
            }
        }
    }
}

// ------------------------------------------------------------ bf16 MFMA GEMM
// EPI: 5 = plain bf16 store (BK=32),
// 6 = +embrow[t[m]][n] (bf16 table, LDS-gathered via batched glds16) + relu + bf16
//     (TILE==128 only, BK=32),
// 4 = fused loss (BK=64): acc -> LDS scoreboard -> per-(row,cat) linear-space
//     loss, atomic accumulate only (finalize is a separate kernel).
template <int EPI, int TILE>
__global__ __launch_bounds__(256) void gemm_mfma(
    const __hip_bfloat16* __restrict__ A, const __hip_bfloat16* __restrict__ Bt,
    const float* __restrict__ bias, void* __restrict__ Cout,
    int M, int Kd, int Nreal, int Cstride,
    const int* __restrict__ tidx, const float* __restrict__ rowbias,
    const int* __restrict__ x_cat, const int* __restrict__ t_in,
    const int* __restrict__ hot, const float* __restrict__ noise,
    const float* __restrict__ sched, double* __restrict__ acc_out) {
    constexpr int FM  = TILE / 32;      // MFMA frags per wave per dim
    constexpr int BK  = (EPI == 4) ? 64 : 32;
    constexpr int KCH = BK / 32;        // 32-wide k-halves per K-iter
    constexpr int RCH = TILE / 16;      // 16-row chunks per matrix per half
    constexpr int CPM2 = RCH * KCH;     // chunks per matrix
    constexpr int CPW2 = CPM2 / 2;      // chunks per wave (4 waves, 2 matrices)
    constexpr int STAGE = 4 * KCH * TILE * 32;   // As+Bs bytes
    constexpr int SCORE = TILE * TILE * 4;
    constexpr int SMEM_BYTES = (EPI == 4) ? (SCORE > STAGE ? SCORE : STAGE)
                               : (EPI == 6) ? (STAGE + TILE * TILE * 2)
                               : STAGE;
    __shared__ __align__(16) char SMEM[SMEM_BYTES];
    __hip_bfloat16* As = (__hip_bfloat16*)SMEM;            // [KCH][TILE][32]
    __hip_bfloat16* Bs = As + KCH * TILE * 32;

    const int tid = threadIdx.x;
    const int lane = tid & 63, wave = tid >> 6;
    const int wm = wave >> 1, wn = wave & 1;

    // XCD swizzle (same-m n-blocks consecutive within one XCD)
    int mb, nb;
    {
        int nbx = gridDim.x, nby = gridDim.y;
        int b = blockIdx.y * nbx + blockIdx.x;
        if ((nby & 7) == 0) {
            int x = b & 7, g = b >> 3;
            nb = g % nbx;
            mb = x + 8 * (g / nbx);
        } else { mb = blockIdx.y; nb = blockIdx.x; }
    }
    const int m0 = mb * TILE, n0 = nb * TILE;

    const __hip_bfloat16* gsrc[CPW2];
    char* ldst[CPW2];
#pragma unroll
    for (int ii = 0; ii < CPW2; ++ii) {
        int gc = wave * CPW2 + ii;
        int mat = gc / CPM2, rem = gc % CPM2;
        int h = rem / RCH, rc = rem % RCH;
        int row = rc * 16 + (lane >> 2);
        int col = h * 32 + (lane & 3) * 8;
        size_t loff = ((size_t)h * TILE * 32 + (size_t)rc * 16 * 32) * 2;
        if (mat == 0) {
            int r = m0 + row; if (r > M - 1) r = M - 1;
            gsrc[ii] = A + (size_t)r * Kd + col;
            ldst[ii] = (char*)As + loff;
        } else {
            int r = n0 + row;
            gsrc[ii] = Bt + (size_t)r * Kd + col;
            ldst[ii] = (char*)Bs + loff;
        }
    }

    if (EPI == 6) {
        char* LE = SMEM + STAGE;
        const __hip_bfloat16* embp = (const __hip_bfloat16*)rowbias;
        int tvec = tidx[m0 + wave * 32 + (lane & 31)];
#pragma unroll
        for (int b = 0; b < 8; ++b) {
            int trow = __shfl(tvec, b * 4 + (lane >> 4));
            glds16((const char*)(embp + (size_t)trow * 1024 + n0) + (lane & 15) * 16,
                   LE + (wave * 32 + b * 4) * 256);
        }
    }

    f32x4 acc[FM][FM] = {};
    const int q8 = (lane >> 4) * 8;
    const int l15 = lane & 15;

    for (int k0 = 0; k0 < Kd; k0 += BK) {
#pragma unroll
        for (int ii = 0; ii < CPW2; ++ii) glds16(gsrc[ii] + k0, ldst[ii]);
        __syncthreads();
#pragma unroll
        for (int kk = 0; kk < KCH; ++kk) {
            short8 af[FM], bfr[FM];
#pragma unroll
            for (int i = 0; i < FM; ++i) {
                af[i]  = *(const short8*)(As + (size_t)kk * TILE * 32 +
                                          (size_t)(wm * (TILE / 2) + i * 16 + l15) * 32 + q8);
                bfr[i] = *(const short8*)(Bs + (size_t)kk * TILE * 32 +
                                          (size_t)(wn * (TILE / 2) + i * 16 + l15) * 32 + q8);
            }
#pragma unroll
            for (int i = 0; i < FM; ++i)
#pragma unroll
                for (int j = 0; j < FM; ++j)
                    acc[i][j] = __builtin_amdgcn_mfma_f32_16x16x32_bf16(
                        af[i], bfr[j], acc[i][j], 0, 0, 0);
        }
        __syncthreads();
    }

    if (EPI == 4) {
        // Phase 1: dump raw acc to LDS scoreboard S[TILE][TILE] (f32, swizzled
        // col' = (col+row)&(TILE-1)). acc dies here -> no spill in K-loop.
        float* S = (float*)SMEM;
#pragma unroll
        for (int i = 0; i < FM; ++i) {
            int rbase = wm * (TILE / 2) + i * 16 + (lane >> 4) * 4;
#pragma unroll
            for (int j = 0; j < FM; ++j) {
                int lcol = wn * (TILE / 2) + j * 16 + l15;
#pragma unroll
                for (int r = 0; r < 4; ++r) {
                    int row = rbase + r;
                    S[row * TILE + ((lcol + row) & (TILE - 1))] = acc[i][j][r];
                }
            }
        }
        __syncthreads();

        // Phase 2: one (row, 16-col-group) pair per thread; linear-space loss.
        double local = 0.0;
        const float* ltbl = rowbias;
        constexpr int PAIRS = TILE * (TILE / 16);
        for (int p = tid; p < PAIRS; p += 256) {
            int ml = p & (TILE - 1), cg = p / TILE;
            int colbase = n0 + cg * 16;
            if (colbase >= 400) continue;
            int m = m0 + ml;
            float ocv[16];
#pragma unroll
            for (int k = 0; k < 16; ++k)
                ocv[k] = S[ml * TILE + ((cg * 16 + k + ml) & (TILE - 1))] + bias[colbase + k];
            if (colbase == 0) {
#pragma unroll
                for (int k = 0; k < 16; ++k) {
                    float d = noise[(size_t)m * 16 + k] - ocv[k];
                    local += (double)(d * d) * (1.0 / (16.0 * BATCH));
                }
            } else {
                int c = (colbase - 16) >> 4;
                int t = t_in[m];
                int xc = x_cat[m * 24 + c];
                int s = hot[m * 24 + c];
                const float* tb = ltbl + t * 8;
                float A1 = tb[0], B1 = tb[1], B1p = tb[2], Qh = tb[3], Qo = tb[4];
                float mx = -3e38f;
#pragma unroll
                for (int k = 0; k < 16; ++k) mx = fmaxf(mx, ocv[k]);
                float E[16];
                float sm = 0.0f;
#pragma unroll
                for (int k = 0; k < 16; ++k) { E[k] = expf(ocv[k] - mx); sm += E[k]; }
                float A1s = A1 / sm;
                float SU = 0.0f, slU = 0.0f, lUxc = 0.0f, lUs = 0.0f;
#pragma unroll
                for (int k = 0; k < 16; ++k) {
                    float U = (E[k] * A1s + B1) * ((k == s) ? Qh : Qo);
                    SU += U;
                    float l = logf(fmaxf(U, 1e-37f));
                    slU += l;
                    if (k == xc) lUxc = l;
                    if (k == s)  lUs = l;
                }
                float lSU = logf(SU);
                float Wh, Ws, Wo, C;
                if (t == 0) {
                    Wh = 1.0f; Ws = 1e-30f; Wo = 1e-30f; C = 0.0f;
                } else {
                    int e = (xc == s);
                    float UTh = (A1 + B1) * (e ? Qh : Qo);
                    float UTs = B1p * Qh;
                    float UTo = B1p * Qo;
                    float ST = e ? (UTh + 15.0f * UTo) : (UTh + UTs + 14.0f * UTo);
                    float rST = 1.0f / ST;
                    Wh = UTh * rST; Wo = UTo * rST; Ws = UTs * rST;
                    C = e ? tb[6] : tb[5];
                }
                float wsTerm = (xc == s) ? 0.0f : (Ws - Wo);
                float SPU = Wo * slU + (Wh - Wo) * lUxc + wsTerm * lUs;
                float Lt = C - SPU + lSU;
                local += (double)Lt * (1.0 / (24.0 * BATCH));
            }
        }
        for (int off = 32; off > 0; off >>= 1)
            local += __shfl_down(local, off);
        __syncthreads();
        double* wred = (double*)SMEM;
        if (lane == 0) wred[wave] = local;
        __syncthreads();
        if (tid == 0)
            atomicAdd(acc_out, wred[0] + wred[1] + wred[2] + wred[3]);
        return;
    }

    const __hip_bfloat16* LE = (const __hip_bfloat16*)(SMEM + STAGE);
#pragma unroll
    for (int i = 0; i < FM; ++i) {
        int mlbase = wm * (TILE / 2) + i * 16 + (lane >> 4) * 4;
#pragma unroll
        for (int j = 0; j < FM; ++j) {
            int nl = wn * (TILE / 2) + j * 16 + l15;
            int n = n0 + nl;
            if (n >= Nreal) continue;
            float bv = bias[n];
#pragma unroll
            for (int r = 0; r < 4; ++r) {
                int ml = mlbase + r;
                int m = m0 + ml;
                if (m >= M) continue;
                float v = acc[i][j][r] + bv;
                if (EPI == 6) { v += __bfloat162float(LE[ml * TILE + nl]); v = fmaxf(v, 0.0f); }
                ((__hip_bfloat16*)Cout)[(size_t)m * Cstride + n] = __float2bfloat16(v);
            }
        }
    }
}

__global__ void finalize_kernel(const double* __restrict__ acc,
                                const float* __restrict__ sched,
                                float* __restrict__ out) {
    // kl_prior is identical for every (sample, category): add once.
    float lcaT = sched[2999];
    float l1mT = sched[3999] - LOGKF;
    float ph = lae(lcaT, l1mT);
    float po = lae(L30F + lcaT, l1mT);
    float prior = expf(ph) * (ph + LOGKF) + 15.0f * expf(po) * (po + LOGKF);
    out[0] = (float)(*acc + (double)prior);
}

extern "C" void kernel_launch(void* const* d_in, const int* in_sizes, int n_in,
                              void* d_out, int out_size, void* d_ws, size_t ws_size,
                              hipStream_t stream) {
    const float* x_num  = (const float*)d_in[0];
    const int*   x_cat  = (const int*)d_in[1];
    const int*   t_in   = (const int*)d_in[2];
    const float* noise  = (const float*)d_in[3];
    const float* gum    = (const float*)d_in[4];
    const float* te_w1  = (const float*)d_in[5];
    const float* te_b1  = (const float*)d_in[6];
    const float* te_w2  = (const float*)d_in[7];
    const float* te_b2  = (const float*)d_in[8];
    const float* proj_w = (const float*)d_in[9];
    const float* proj_b = (const float*)d_in[10];
    const float* mlp_w1 = (const float*)d_in[11];
    const float* mlp_b1 = (const float*)d_in[12];
    const float* mlp_w2 = (const float*)d_in[13];
    const float* mlp_b2 = (const float*)d_in[14];
    float* out = (float*)d_out;

    char* w = (char*)d_ws;
    size_t off = 0;
    auto alloc = [&](size_t bytes) {
        void* p = w + off;
        off += (bytes + 1023) & ~(size_t)1023;
        return p;
    };
    double* acc     = (double*)alloc(1024);
    float* sched    = (float*)alloc(6 * 1000 * 4);
    float* ltbl     = (float*)alloc(8 * 1000 * 4);
    int*   hot      = (int*)alloc((size_t)BATCH * 24 * 4);
    float* colconst = (float*)alloc(1024 * 4);
    float* zbias    = (float*)alloc(1024 * 4);
    float* bias2    = (float*)alloc(1024 * 4);
    __hip_bfloat16* E0    = (__hip_bfloat16*)alloc((size_t)1024 * 1024 * 2);
    __hip_bfloat16* E1    = (__hip_bfloat16*)alloc((size_t)1024 * 1024 * 2);
    __hip_bfloat16* EMB2  = (__hip_bfloat16*)alloc((size_t)1024 * 1024 * 2);
    __hip_bfloat16* tw1t  = (__hip_bfloat16*)alloc((size_t)1024 * 1024 * 2);
    __hip_bfloat16* tw2b  = (__hip_bfloat16*)alloc((size_t)1024 * 1024 * 2);
    __hip_bfloat16* W12t  = (__hip_bfloat16*)alloc((size_t)1024 * 1024 * 2);
    __hip_bfloat16* w1t   = (__hip_bfloat16*)alloc((size_t)1024 * 1024 * 2);
    __hip_bfloat16* w2t   = (__hip_bfloat16*)alloc((size_t)512 * 1024 * 2);
    __hip_bfloat16* pjb   = (__hip_bfloat16*)alloc((size_t)448 * 1024 * 2);
    __hip_bfloat16* PWT   = (__hip_bfloat16*)alloc((size_t)1024 * 416 * 2);
    __hip_bfloat16* X     = (__hip_bfloat16*)alloc((size_t)BATCH * 416 * 2);
    __hip_bfloat16* R     = (__hip_bfloat16*)alloc((size_t)BATCH * 1024 * 2);

    // 1) setup: transposes + casts + E0 + colconst + schedules/ltbl + acc zero
    setup_all<<<7301, 256, 0, stream>>>(te_w1, mlp_w1, mlp_w2, te_w2,
                                        tw1t, w1t, w2t, pjb, tw2b,
                                        E0, proj_w, proj_b, te_b2,
                                        colconst, zbias, sched, ltbl, acc);
    // 2) mid: bias2 + PWT + E1 + W12t + prep_x
    mid_all<<<1664, 256, 0, stream>>>(x_num, x_cat, t_in, noise, gum, sched, X, hot,
                                      w1t, pjb, tw2b, E0, tw1t, te_b1, zbias,
                                      PWT, E1, W12t, colconst, mlp_b1, bias2);
    // 3) EMB2 = E1 @ W12t^T + bias2   [per-t hidden-layer bias table]
    gemm_mfma<5, 64><<<dim3(16, 16), 256, 0, stream>>>(
        E1, W12t, bias2, EMB2, 1000, 1024, 1024, 1024,
        nullptr, nullptr, nullptr, nullptr, nullptr, nullptr, nullptr, nullptr);
    // 4) R = relu(X @ PWT^T + EMB2[t])
    gemm_mfma<6, 128><<<dim3(8, 128), 256, 0, stream>>>(
        X, PWT, zbias, R, BATCH, 416, 1024, 1024,
        t_in, (const float*)EMB2, nullptr, nullptr, nullptr, nullptr, nullptr, nullptr);
    // 5) loss: (R @ mlp_w2 + mlp_b2) -> scoreboard -> linear-space loss (BK=64)
    gemm_mfma<4, 64><<<dim3(7, 256), 256, 0, stream>>>(
        R, w2t, mlp_b2, nullptr, BATCH, 1024, 400, 0,
        nullptr, ltbl, x_cat, t_in, hot, noise, sched, acc);
    // 6) finalize
    finalize_kernel<<<1, 1, 0, stream>>>(acc, sched, out);
}

// Round 14
// 240.026 us; speedup vs baseline: 1.2718x; 1.0721x over previous
//
#include <hip/hip_runtime.h>
#include <hip/hip_bf16.h>
#include <math.h>

#define BATCH 16384
#define NCAT 24

// log(1e-30f), log(16)
#define L30F  (-69.07755279f)
#define LOGKF (2.7725887f)

typedef __attribute__((ext_vector_type(8))) short short8;
typedef __attribute__((ext_vector_type(4))) float f32x4;

__device__ __forceinline__ float lae(float a, float b) {
    float m = fmaxf(a, b);
    return m + logf(expf(a - m) + expf(b - m));
}

__device__ __forceinline__ void glds16(const void* g, void* l) {
    __builtin_amdgcn_global_load_lds((const __attribute__((address_space(1))) void*)g,
                                     (__attribute__((address_space(3))) void*)l,
                                     16, 0, 0);
}

// ------------------------------- fused setup (one launch) --------------------
// [0,2560): transposes {te_w1->tw1t, mlp_w1->w1t, mlp_w2->w2t} f32->bf16 [Npad x 1024]
// [2560,2784): pjb  = bf16(proj_w)  [448 x 1024], rows >= 400 zero
// [2784,3296): tw2b = bf16(te_w2)   [1024 x 1024] (no transpose)
// [3296,7296): E0 bf16 timestep-embedding table (1000x1024)
// [7296,7300): colconst[j] = te_b2[j]+proj_b[j]+L30F*sum proj_w[16:400][j]; zbias=0
// 7300: schedules + per-t loss table + acc zero
__global__ __launch_bounds__(256) void setup_all(
    const float* __restrict__ te_w1, const float* __restrict__ mlp_w1,
    const float* __restrict__ mlp_w2, const float* __restrict__ te_w2,
    __hip_bfloat16* __restrict__ tw1t, __hip_bfloat16* __restrict__ w1t,
    __hip_bfloat16* __restrict__ w2t,
    __hip_bfloat16* __restrict__ pjb, __hip_bfloat16* __restrict__ tw2b,
    __hip_bfloat16* __restrict__ E0, const float* __restrict__ proj_w,
    const float* __restrict__ proj_b, const float* __restrict__ te_b2,
    float* __restrict__ colconst, float* __restrict__ zbias,
    float* __restrict__ sched, float* __restrict__ ltbl,
    double* __restrict__ acc) {
    const int bid = blockIdx.x, tid = threadIdx.x;
    if (bid < 2560) {
        // transpose: W[K x Nw] f32 -> Wt[Npad x 1024] bf16 (zero pad)
        const int boff[4] = {0, 1024, 2048, 2560};
        const int nxs[3]  = {32, 32, 16};
        const int Nws[3]  = {1024, 1024, 400};
        const int Nps[3]  = {1024, 1024, 512};
        int job = 0;
#pragma unroll
        for (int j = 1; j < 3; ++j) job += (bid >= boff[j]) ? 1 : 0;
        const float* W = (job == 0) ? te_w1 : (job == 1) ? mlp_w1 : mlp_w2;
        __hip_bfloat16* Wt = (job == 0) ? tw1t : (job == 1) ? w1t : w2t;
        const int lb = bid - boff[job];
        const int Nw = Nws[job], Npad = Nps[job];
        const int n0 = (lb % nxs[job]) * 32, k0 = (lb / nxs[job]) * 32;
        __shared__ float t[32][33];
        int c = tid & 31, r8 = tid >> 5;
#pragma unroll
        for (int i = 0; i < 32; i += 8) {
            int k = k0 + r8 + i, n = n0 + c;
            t[r8 + i][c] = (n < Nw) ? W[(size_t)k * Nw + n] : 0.0f;
        }
        __syncthreads();
#pragma unroll
        for (int i = 0; i < 32; i += 8) {
            int n = n0 + r8 + i, k = k0 + c;
            if (n < Npad) Wt[(size_t)n * 1024 + k] = __float2bfloat16(t[c][r8 + i]);
        }
    } else if (bid < 2784) {
        int idx = (bid - 2560) * 2048 + tid * 8;
        int r = idx >> 10;
        __hip_bfloat16 v[8];
        if (r < 400) {
            const float* src = proj_w + idx;
#pragma unroll
            for (int q = 0; q < 8; ++q) v[q] = __float2bfloat16(src[q]);
        } else {
#pragma unroll
            for (int q = 0; q < 8; ++q) v[q] = __float2bfloat16(0.0f);
        }
        *(short8*)(pjb + idx) = *(const short8*)v;
    } else if (bid < 3296) {
        int idx = (bid - 2784) * 2048 + tid * 8;
        const float* src = te_w2 + idx;
        __hip_bfloat16 v[8];
#pragma unroll
        for (int q = 0; q < 8; ++q) v[q] = __float2bfloat16(src[q]);
        *(short8*)(tw2b + idx) = *(const short8*)v;
    } else if (bid < 7296) {
        int gid = (bid - 3296) * 256 + tid;
        int t = gid >> 10, j = gid & 1023;
        int jj = (j < 512) ? j : j - 512;
        float freq = expf(-logf(10000.0f) * (float)jj / 512.0f);
        float arg = (float)t * freq;
        E0[gid] = __float2bfloat16((j < 512) ? cosf(arg) : sinf(arg));
    } else if (bid < 7300) {
        int j = (bid - 7296) * 256 + tid;
        float s = 0.0f;
        for (int r = 16; r < 400; ++r) s += proj_w[(size_t)r * 1024 + j];
        colconst[j] = te_b2[j] + proj_b[j] + L30F * s;
        zbias[j] = 0.0f;
    } else {
        __shared__ double la_s[1000];
        __shared__ double lca_s[1000];
        const double PI = 3.14159265358979323846;
        for (int i = tid; i < 1000; i += 256) {
            double u0 = ((double)i / 1000.0 + 0.008) / 1.008 * PI * 0.5;
            double u1 = ((double)(i + 1) / 1000.0 + 0.008) / 1.008 * PI * 0.5;
            double c0 = cos(u0), c1 = cos(u1);
            double beta = 1.0 - (c1 * c1) / (c0 * c0);
            if (beta > 0.999) beta = 0.999;
            la_s[i] = log(1.0 - beta);
        }
        __syncthreads();
        if (tid == 0) {
            double run = 0.0;
            for (int i = 0; i < 1000; ++i) { run += la_s[i]; lca_s[i] = run; }
            *acc = 0.0;
        }
        __syncthreads();
        for (int i = tid; i < 1000; i += 256) {
            double la = la_s[i], lca = lca_s[i];
            sched[i]        = (float)la;
            sched[1000 + i] = (float)log(1.0 - exp(la) + 1e-40);
            sched[2000 + i] = (float)lca;
            sched[3000 + i] = (float)log(1.0 - exp(lca) + 1e-40);
            sched[4000 + i] = (float)sqrt(exp(lca));
            sched[5000 + i] = (float)sqrt(1.0 - exp(lca));
            // per-t loss table: {A1, B1, B1p, Qh, Qo, C0 (xc!=s), C1 (xc==s), 0}
            double alpha = exp(la);
            double A1, B1;
            if (i == 0) { A1 = 1.0; B1 = 0.0; }
            else { double ab = exp(lca_s[i - 1]); A1 = ab; B1 = (1.0 - ab) / 16.0; }
            double B1p = 1e-30 * A1 + B1;
            double Qh = alpha + (1.0 - alpha) / 16.0;
            double Qo = 1e-30 * alpha + (1.0 - alpha) / 16.0;
            double C0 = 0.0, C1 = 0.0;
            if (i > 0) {
                double UTh1 = (A1 + B1) * Qh, UTo = B1p * Qo, UTs = B1p * Qh;
                double ST1 = UTh1 + 15.0 * UTo;
                double p1 = UTh1 / ST1, p0 = UTo / ST1;
                C1 = p1 * log(p1) + 15.0 * p0 * log(p0);
                double UTh0 = (A1 + B1) * Qo;
                double ST0 = UTh0 + UTs + 14.0 * UTo;
                double pxc = UTh0 / ST0, ps = UTs / ST0, po = UTo / ST0;
                C0 = pxc * log(pxc) + ps * log(ps) + 14.0 * po * log(po);
            }
            ltbl[i * 8 + 0] = (float)A1;
            ltbl[i * 8 + 1] = (float)B1;
            ltbl[i * 8 + 2] = (float)B1p;
            ltbl[i * 8 + 3] = (float)Qh;
            ltbl[i * 8 + 4] = (float)Qo;
            ltbl[i * 8 + 5] = (float)C0;
            ltbl[i * 8 + 6] = (float)C1;
            ltbl[i * 8 + 7] = 0.0f;
        }
    }
}

// ------------------ runtime-epi 64-tile GEMM body (used by mid_all) ----------
// C[M,Nreal] = (silu?)(A @ Bt^T + bias), bf16 out. BK=32, 4 waves 2x2, 2x2 frags.
__device__ __forceinline__ void gemm64_body(
    bool silu, const __hip_bfloat16* A, const __hip_bfloat16* Bt,
    const float* bias, __hip_bfloat16* C, int M, int Kd, int Nreal,
    int Cstride, int mb, int nb, char* smem, int tid) {
    __hip_bfloat16* As = (__hip_bfloat16*)smem;
    __hip_bfloat16* Bs = As + 64 * 32;
    const int lane = tid & 63, wave = tid >> 6;
    const int wm = wave >> 1, wn = wave & 1;
    const int m0 = mb * 64, n0 = nb * 64;

    const __hip_bfloat16* gsrc[2];
    char* ldst[2];
#pragma unroll
    for (int ii = 0; ii < 2; ++ii) {
        int gc = wave * 2 + ii;
        int mat = gc >> 2, rem = gc & 3;
        int row = rem * 16 + (lane >> 2);
        int col = (lane & 3) * 8;
        if (mat == 0) {
            int r = m0 + row; if (r > M - 1) r = M - 1;
            gsrc[ii] = A + (size_t)r * Kd + col;
            ldst[ii] = (char*)As + rem * 1024;
        } else {
            int r = n0 + row;
            gsrc[ii] = Bt + (size_t)r * Kd + col;
            ldst[ii] = (char*)Bs + rem * 1024;
        }
    }
    f32x4 acc[2][2] = {};
    const int q8 = (lane >> 4) * 8;
    const int l15 = lane & 15;
    for (int k0 = 0; k0 < Kd; k0 += 32) {
        glds16(gsrc[0] + k0, ldst[0]);
        glds16(gsrc[1] + k0, ldst[1]);
        __syncthreads();
        short8 af[2], bfr[2];
#pragma unroll
        for (int i = 0; i < 2; ++i) {
            af[i]  = *(const short8*)(As + (size_t)(wm * 32 + i * 16 + l15) * 32 + q8);
            bfr[i] = *(const short8*)(Bs + (size_t)(wn * 32 + i * 16 + l15) * 32 + q8);
        }
#pragma unroll
        for (int i = 0; i < 2; ++i)
#pragma unroll
            for (int j = 0; j < 2; ++j)
                acc[i][j] = __builtin_amdgcn_mfma_f32_16x16x32_bf16(
                    af[i], bfr[j], acc[i][j], 0, 0, 0);
        __syncthreads();
    }
#pragma unroll
    for (int i = 0; i < 2; ++i) {
        int mbase = m0 + wm * 32 + i * 16 + (lane >> 4) * 4;
#pragma unroll
        for (int j = 0; j < 2; ++j) {
            int n = n0 + wn * 32 + j * 16 + l15;
            if (n >= Nreal) continue;
            float bv = bias[n];
#pragma unroll
            for (int r = 0; r < 4; ++r) {
                int m = mbase + r;
                if (m >= M) continue;
                float v = acc[i][j][r] + bv;
                if (silu) v = v / (1.0f + expf(-v));
                C[(size_t)m * Cstride + n] = __float2bfloat16(v);
            }
        }
    }
}

// ------------------- mid: bias2 + PWT + E1 + W12t + prep_x (one launch) ------
// [0,16): bias2[k] = dot(w1t_row_k, colconst) + mlp_b1[k]   (64 k's per block)
// [16,128): PWT [1024x448]  [128,384): E1   [384,640): W12t   [640,1664): prep_x
__global__ __launch_bounds__(256) void mid_all(
    const float* __restrict__ x_num, const int* __restrict__ x_cat,
    const int* __restrict__ t_in, const float* __restrict__ noise,
    const float* __restrict__ gum, const float* __restrict__ sched,
    __hip_bfloat16* __restrict__ X, int* __restrict__ hot,
    const __hip_bfloat16* __restrict__ w1t, const __hip_bfloat16* __restrict__ pjb,
    const __hip_bfloat16* __restrict__ tw2b, const __hip_bfloat16* __restrict__ E0,
    const __hip_bfloat16* __restrict__ tw1t,
    const float* __restrict__ te_b1, const float* __restrict__ zbias,
    __hip_bfloat16* __restrict__ PWT, __hip_bfloat16* __restrict__ E1,
    __hip_bfloat16* __restrict__ W12t,
    const float* __restrict__ colconst, const float* __restrict__ mlp_b1,
    float* __restrict__ bias2) {
    __shared__ __align__(16) char SM[8192];
    const int bid = blockIdx.x, tid = threadIdx.x;
    if (bid < 16) {
        // ---- bias2: per wave, 16 k's; per k: 64-lane dot over 1024 elements
        const int lane = tid & 63, wave = tid >> 6;
        for (int kk = 0; kk < 16; ++kk) {
            int k = bid * 64 + wave * 16 + kk;
            const __hip_bfloat16* row = w1t + (size_t)k * 1024 + lane * 16;
            const float* cc = colconst + lane * 16;
            float s = 0.0f;
#pragma unroll
            for (int q = 0; q < 16; ++q)
                s = fmaf(__bfloat162float(row[q]), cc[q], s);
            for (int off = 32; off > 0; off >>= 1)
                s += __shfl_down(s, off);
            if (lane == 0) bias2[k] = s + mlp_b1[k];
        }
    } else if (bid < 128) {
        // ---- PWT[j,k] = sum_n w1[n,j] proj_w[k,n] -> [1024 x 448] (cols 416+ = 0)
        int lb = bid - 16;
        gemm64_body(false, w1t, pjb, zbias, PWT, 1024, 1024, 448, 448,
                    lb / 7, lb % 7, SM, tid);
    } else if (bid < 384) {
        // ---- E1 = silu(E0 @ te_w1 + te_b1)  [1000 x 1024]
        int lb = bid - 128;
        gemm64_body(true, E0, tw1t, te_b1, E1, 1000, 1024, 1024, 1024,
                    lb >> 4, lb & 15, SM, tid);
    } else if (bid < 640) {
        // ---- W12t[k,n] = sum_j w1[j,k] te_w2[n,j]  ( = (te_w2@w1)^T )
        int lb = bid - 384;
        gemm64_body(false, w1t, tw2b, zbias, W12t, 1024, 1024, 1024, 1024,
                    lb >> 4, lb & 15, SM, tid);
    } else {
        // ---- prep_x: gumbel argmax + build X[B x 448] bf16 (cols 416+ = 0)
        float* xnt = (float*)SM;                    // [16][16]
        int* sh_hot = (int*)(SM + 1024);            // [16][24]
        int* sh_t = (int*)(SM + 1024 + 1536);       // [16]
        const int b0 = (bid - 640) * 16;
        const float* LOG_CA = sched + 2000;
        const float* LOG_1M_CA = sched + 3000;
        const float* SQ_AC = sched + 4000;
        const float* SQ_1M = sched + 5000;
        if (tid < 16) sh_t[tid] = t_in[b0 + tid];
        __syncthreads();
        {
            int r = tid >> 4, i = tid & 15;
            int t = sh_t[r];
            xnt[r * 16 + i] = SQ_AC[t] * x_num[(size_t)(b0 + r) * 16 + i] +
                              SQ_1M[t] * noise[(size_t)(b0 + r) * 16 + i];
        }
        for (int task = tid; task < 16 * 24; task += 256) {
            int r = task / 24, c = task - r * 24;
            int t = sh_t[r];
            int xc = x_cat[(size_t)(b0 + r) * 24 + c];
            float l1 = LOG_1M_CA[t] - LOGKF;
            float lca = LOG_CA[t];
            float vh = lae(lca, l1);
            float vo = lae(L30F + lca, l1);
            const float* gu = gum + (size_t)(b0 + r) * 384 + c * 16;
            float best = -3.0e38f;
            int bi = 0;
#pragma unroll
            for (int k = 0; k < 16; ++k) {
                float g = -logf(-logf(gu[k] + 1e-30f) + 1e-30f);
                float v = g + ((k == xc) ? vh : vo);
                if (v > best) { best = v; bi = k; }
            }
            sh_hot[r * 24 + c] = bi;
            hot[(size_t)(b0 + r) * 24 + c] = bi;
        }
        __syncthreads();
        const float DELTA = 69.07755279f;  // -L30F
#pragma unroll
        for (int it = 0; it < 4; ++it) {
            int idx = it * 256 + tid;          // 16*56 = 896 short8 stores
            if (idx < 896) {
                int r = idx / 56, jc = idx - r * 56;
                int j0 = jc * 8;
                __hip_bfloat16 v[8];
#pragma unroll
                for (int qq = 0; qq < 8; ++qq) {
                    int j = j0 + qq;
                    float f = 0.0f;
                    if (j < 16) {
                        f = xnt[r * 16 + j];
                    } else if (j < 400) {
                        int c = (j - 16) >> 4, k = (j - 16) & 15;
                        f = (sh_hot[r * 24 + c] == k) ? DELTA : 0.0f;
                    }
                    v[qq] = __float2bfloat16(f);
                }
                *(short8*)(X + (size_t)(b0 + r) * 448 + j0) = *(const short8*)v;
            }
        }
    }
}

// ------------------------------------------------------------ bf16 MFMA GEMM
// EPI: 5 = plain bf16 store (BK=32),
// 6 = +embrow[t[m]][n] (bf16 table, LDS-gathered via batched glds16) + relu + bf16
//     (BK=64),
// 4 = fused loss (BK=64): acc -> LDS scoreboard -> per-(row,cat) linear-space
//     loss, atomic accumulate only (finalize is a separate kernel).
template <int EPI, int TILE>
__global__ __launch_bounds__(256) void gemm_mfma(
    const __hip_bfloat16* __restrict__ A, const __hip_bfloat16* __restrict__ Bt,
    const float* __restrict__ bias, void* __restrict__ Cout,
    int M, int Kd, int Nreal, int Cstride,
    const int* __restrict__ tidx, const float* __restrict__ rowbias,
    const int* __restrict__ x_cat, const int* __restrict__ t_in,
    const int* __restrict__ hot, const float* __restrict__ noise,
    const float* __restrict__ sched, double* __restrict__ acc_out) {
    constexpr int FM  = TILE / 32;      // MFMA frags per wave per dim
    constexpr int BK  = (EPI == 4 || EPI == 6) ? 64 : 32;
    constexpr int KCH = BK / 32;        // 32-wide k-halves per K-iter
    constexpr int RCH = TILE / 16;      // 16-row chunks per matrix per half
    constexpr int CPM2 = RCH * KCH;     // chunks per matrix
    constexpr int CPW2 = CPM2 / 2;      // chunks per wave (4 waves, 2 matrices)
    constexpr int STAGE = 4 * KCH * TILE * 32;   // As+Bs bytes
    constexpr int SCORE = TILE * TILE * 4;
    constexpr int SMEM_BYTES = (EPI == 4) ? (SCORE > STAGE ? SCORE : STAGE)
                               : (EPI == 6) ? (STAGE + TILE * TILE * 2)
                               : STAGE;
    __shared__ __align__(16) char SMEM[SMEM_BYTES];
    __hip_bfloat16* As = (__hip_bfloat16*)SMEM;            // [KCH][TILE][32]
    __hip_bfloat16* Bs = As + KCH * TILE * 32;

    const int tid = threadIdx.x;
    const int lane = tid & 63, wave = tid >> 6;
    const int wm = wave >> 1, wn = wave & 1;

    // XCD swizzle (same-m n-blocks consecutive within one XCD)
    int mb, nb;
    {
        int nbx = gridDim.x, nby = gridDim.y;
        int b = blockIdx.y * nbx + blockIdx.x;
        if ((nby & 7) == 0) {
            int x = b & 7, g = b >> 3;
            nb = g % nbx;
            mb = x + 8 * (g / nbx);
        } else { mb = blockIdx.y; nb = blockIdx.x; }
    }
    const int m0 = mb * TILE, n0 = nb * TILE;

    const __hip_bfloat16* gsrc[CPW2];
    char* ldst[CPW2];
#pragma unroll
    for (int ii = 0; ii < CPW2; ++ii) {
        int gc = wave * CPW2 + ii;
        int mat = gc / CPM2, rem = gc % CPM2;
        int h = rem / RCH, rc = rem % RCH;
        int row = rc * 16 + (lane >> 2);
        int col = h * 32 + (lane & 3) * 8;
        size_t loff = ((size_t)h * TILE * 32 + (size_t)rc * 16 * 32) * 2;
        if (mat == 0) {
            int r = m0 + row; if (r > M - 1) r = M - 1;
            gsrc[ii] = A + (size_t)r * Kd + col;
            ldst[ii] = (char*)As + loff;
        } else {
            int r = n0 + row;
            gsrc[ii] = Bt + (size_t)r * Kd + col;
            ldst[ii] = (char*)Bs + loff;
        }
    }

    // EPI==6: gather the block's TILE rowbias rows (bf16, TILE*2 B each) into
    // LDS via batched glds16 (per-lane global addr, wave-uniform LDS base).
    if (EPI == 6) {
        char* LE = SMEM + STAGE;
        const __hip_bfloat16* embp = (const __hip_bfloat16*)rowbias;
        if (TILE == 128) {
            int tvec = tidx[m0 + wave * 32 + (lane & 31)];
#pragma unroll
            for (int b = 0; b < 8; ++b) {
                int trow = __shfl(tvec, b * 4 + (lane >> 4));
                glds16((const char*)(embp + (size_t)trow * 1024 + n0) + (lane & 15) * 16,
                       LE + (wave * 32 + b * 4) * 256);
            }
        } else {  // TILE == 64: rows are 128 B = 8 lanes x 16 B
            int tvec = tidx[m0 + wave * 16 + (lane & 15)];
#pragma unroll
            for (int b = 0; b < 2; ++b) {
                int trow = __shfl(tvec, b * 8 + (lane >> 3));
                glds16((const char*)(embp + (size_t)trow * 1024 + n0) + (lane & 7) * 16,
                       LE + (wave * 16 + b * 8) * 128);
            }
        }
    }

    f32x4 acc[FM][FM] = {};
    const int q8 = (lane >> 4) * 8;
    const int l15 = lane & 15;

    for (int k0 = 0; k0 < Kd; k0 += BK) {
#pragma unroll
        for (int ii = 0; ii < CPW2; ++ii) glds16(gsrc[ii] + k0, ldst[ii]);
        __syncthreads();
#pragma unroll
        for (int kk = 0; kk < KCH; ++kk) {
            short8 af[FM], bfr[FM];
#pragma unroll
            for (int i = 0; i < FM; ++i) {
                af[i]  = *(const short8*)(As + (size_t)kk * TILE * 32 +
                                          (size_t)(wm * (TILE / 2) + i * 16 + l15) * 32 + q8);
                bfr[i] = *(const short8*)(Bs + (size_t)kk * TILE * 32 +
                                          (size_t)(wn * (TILE / 2) + i * 16 + l15) * 32 + q8);
            }
#pragma unroll
            for (int i = 0; i < FM; ++i)
#pragma unroll
                for (int j = 0; j < FM; ++j)
                    acc[i][j] = __builtin_amdgcn_mfma_f32_16x16x32_bf16(
                        af[i], bfr[j], acc[i][j], 0, 0, 0);
        }
        __syncthreads();
    }

    if (EPI == 4) {
        // Phase 1: dump raw acc to LDS scoreboard S[TILE][TILE] (f32, swizzled
        // col' = (col+row)&(TILE-1)). acc dies here -> no spill in K-loop.
        float* S = (float*)SMEM;
#pragma unroll
        for (int i = 0; i < FM; ++i) {
            int rbase = wm * (TILE / 2) + i * 16 + (lane >> 4) * 4;
#pragma unroll
            for (int j = 0; j < FM; ++j) {
                int lcol = wn * (TILE / 2) + j * 16 + l15;
#pragma unroll
                for (int r = 0; r < 4; ++r) {
                    int row = rbase + r;
                    S[row * TILE + ((lcol + row) & (TILE - 1))] = acc[i][j][r];
                }
            }
        }
        __syncthreads();

        // Phase 2: one (row, 16-col-group) pair per thread; linear-space loss.
        double local = 0.0;
        const float* ltbl = rowbias;
        constexpr int PAIRS = TILE * (TILE / 16);
        for (int p = tid; p < PAIRS; p += 256) {
            int ml = p & (TILE - 1), cg = p / TILE;
            int colbase = n0 + cg * 16;
            if (colbase >= 400) continue;
            int m = m0 + ml;
            float ocv[16];
#pragma unroll
            for (int k = 0; k < 16; ++k)
                ocv[k] = S[ml * TILE + ((cg * 16 + k + ml) & (TILE - 1))] + bias[colbase + k];
            if (colbase == 0) {
#pragma unroll
                for (int k = 0; k < 16; ++k) {
                    float d = noise[(size_t)m * 16 + k] - ocv[k];
                    local += (double)(d * d) * (1.0 / (16.0 * BATCH));
                }
            } else {
                int c = (colbase - 16) >> 4;
                int t = t_in[m];
                int xc = x_cat[m * 24 + c];
                int s = hot[m * 24 + c];
                const float* tb = ltbl + t * 8;
                float A1 = tb[0], B1 = tb[1], B1p = tb[2], Qh = tb[3], Qo = tb[4];
                float mx = -3e38f;
#pragma unroll
                for (int k = 0; k < 16; ++k) mx = fmaxf(mx, ocv[k]);
                float E[16];
                float sm = 0.0f;
#pragma unroll
                for (int k = 0; k < 16; ++k) { E[k] = expf(ocv[k] - mx); sm += E[k]; }
                float A1s = A1 / sm;
                float SU = 0.0f, slU = 0.0f, lUxc = 0.0f, lUs = 0.0f;
#pragma unroll
                for (int k = 0; k < 16; ++k) {
                    float U = (E[k] * A1s + B1) * ((k == s) ? Qh : Qo);
                    SU += U;
                    float l = logf(fmaxf(U, 1e-37f));
                    slU += l;
                    if (k == xc) lUxc = l;
                    if (k == s)  lUs = l;
                }
                float lSU = logf(SU);
                float Wh, Ws, Wo, C;
                if (t == 0) {
                    Wh = 1.0f; Ws = 1e-30f; Wo = 1e-30f; C = 0.0f;
                } else {
                    int e = (xc == s);
                    float UTh = (A1 + B1) * (e ? Qh : Qo);
                    float UTs = B1p * Qh;
                    float UTo = B1p * Qo;
                    float ST = e ? (UTh + 15.0f * UTo) : (UTh + UTs + 14.0f * UTo);
                    float rST = 1.0f / ST;
                    Wh = UTh * rST; Wo = UTo * rST; Ws = UTs * rST;
                    C = e ? tb[6] : tb[5];
                }
                float wsTerm = (xc == s) ? 0.0f : (Ws - Wo);
                float SPU = Wo * slU + (Wh - Wo) * lUxc + wsTerm * lUs;
                float Lt = C - SPU + lSU;
                local += (double)Lt * (1.0 / (24.0 * BATCH));
            }
        }
        for (int off = 32; off > 0; off >>= 1)
            local += __shfl_down(local, off);
        __syncthreads();
        double* wred = (double*)SMEM;
        if (lane == 0) wred[wave] = local;
        __syncthreads();
        if (tid == 0)
            atomicAdd(acc_out, wred[0] + wred[1] + wred[2] + wred[3]);
        return;
    }

    const __hip_bfloat16* LE = (const __hip_bfloat16*)(SMEM + STAGE);
#pragma unroll
    for (int i = 0; i < FM; ++i) {
        int mlbase = wm * (TILE / 2) + i * 16 + (lane >> 4) * 4;
#pragma unroll
        for (int j = 0; j < FM; ++j) {
            int nl = wn * (TILE / 2) + j * 16 + l15;
            int n = n0 + nl;
            if (n >= Nreal) continue;
            float bv = bias[n];
#pragma unroll
            for (int r = 0; r < 4; ++r) {
                int ml = mlbase + r;
                int m = m0 + ml;
                if (m >= M) continue;
                float v = acc[i][j][r] + bv;
                if (EPI == 6) { v += __bfloat162float(LE[ml * TILE + nl]); v = fmaxf(v, 0.0f); }
                ((__hip_bfloat16*)Cout)[(size_t)m * Cstride + n] = __float2bfloat16(v);
            }
        }
    }
}

__global__ void finalize_kernel(const double* __restrict__ acc,
                                const float* __restrict__ sched,
                                float* __restrict__ out) {
    // kl_prior is identical for every (sample, category): add once.
    float lcaT = sched[2999];
    float l1mT = sched[3999] - LOGKF;
    float ph = lae(lcaT, l1mT);
    float po = lae(L30F + lcaT, l1mT);
    float prior = expf(ph) * (ph + LOGKF) + 15.0f * expf(po) * (po + LOGKF);
    out[0] = (float)(*acc + (double)prior);
}

extern "C" void kernel_launch(void* const* d_in, const int* in_sizes, int n_in,
                              void* d_out, int out_size, void* d_ws, size_t ws_size,
                              hipStream_t stream) {
    const float* x_num  = (const float*)d_in[0];
    const int*   x_cat  = (const int*)d_in[1];
    const int*   t_in   = (const int*)d_in[2];
    const float* noise  = (const float*)d_in[3];
    const float* gum    = (const float*)d_in[4];
    const float* te_w1  = (const float*)d_in[5];
    const float* te_b1  = (const float*)d_in[6];
    const float* te_w2  = (const float*)d_in[7];
    const float* te_b2  = (const float*)d_in[8];
    const float* proj_w = (const float*)d_in[9];
    const float* proj_b = (const float*)d_in[10];
    const float* mlp_w1 = (const float*)d_in[11];
    const float* mlp_b1 = (const float*)d_in[12];
    const float* mlp_w2 = (const float*)d_in[13];
    const float* mlp_b2 = (const float*)d_in[14];
    float* out = (float*)d_out;

    char* w = (char*)d_ws;
    size_t off = 0;
    auto alloc = [&](size_t bytes) {
        void* p = w + off;
        off += (bytes + 1023) & ~(size_t)1023;
        return p;
    };
    double* acc     = (double*)alloc(1024);
    float* sched    = (float*)alloc(6 * 1000 * 4);
    float* ltbl     = (float*)alloc(8 * 1000 * 4);
    int*   hot      = (int*)alloc((size_t)BATCH * 24 * 4);
    float* colconst = (float*)alloc(1024 * 4);
    float* zbias    = (float*)alloc(1024 * 4);
    float* bias2    = (float*)alloc(1024 * 4);
    __hip_bfloat16* E0    = (__hip_bfloat16*)alloc((size_t)1024 * 1024 * 2);
    __hip_bfloat16* E1    = (__hip_bfloat16*)alloc((size_t)1024 * 1024 * 2);
    __hip_bfloat16* EMB2  = (__hip_bfloat16*)alloc((size_t)1024 * 1024 * 2);
    __hip_bfloat16* tw1t  = (__hip_bfloat16*)alloc((size_t)1024 * 1024 * 2);
    __hip_bfloat16* tw2b  = (__hip_bfloat16*)alloc((size_t)1024 * 1024 * 2);
    __hip_bfloat16* W12t  = (__hip_bfloat16*)alloc((size_t)1024 * 1024 * 2);
    __hip_bfloat16* w1t   = (__hip_bfloat16*)alloc((size_t)1024 * 1024 * 2);
    __hip_bfloat16* w2t   = (__hip_bfloat16*)alloc((size_t)512 * 1024 * 2);
    __hip_bfloat16* pjb   = (__hip_bfloat16*)alloc((size_t)448 * 1024 * 2);
    __hip_bfloat16* PWT   = (__hip_bfloat16*)alloc((size_t)1024 * 448 * 2);
    __hip_bfloat16* X     = (__hip_bfloat16*)alloc((size_t)BATCH * 448 * 2);
    __hip_bfloat16* R     = (__hip_bfloat16*)alloc((size_t)BATCH * 1024 * 2);

    // 1) setup: transposes + casts + E0 + colconst + schedules/ltbl + acc zero
    setup_all<<<7301, 256, 0, stream>>>(te_w1, mlp_w1, mlp_w2, te_w2,
                                        tw1t, w1t, w2t, pjb, tw2b,
                                        E0, proj_w, proj_b, te_b2,
                                        colconst, zbias, sched, ltbl, acc);
    // 2) mid: bias2 + PWT + E1 + W12t + prep_x
    mid_all<<<1664, 256, 0, stream>>>(x_num, x_cat, t_in, noise, gum, sched, X, hot,
                                      w1t, pjb, tw2b, E0, tw1t, te_b1, zbias,
                                      PWT, E1, W12t, colconst, mlp_b1, bias2);
    // 3) EMB2 = E1 @ W12t^T + bias2   [per-t hidden-layer bias table]
    gemm_mfma<5, 64><<<dim3(16, 16), 256, 0, stream>>>(
        E1, W12t, bias2, EMB2, 1000, 1024, 1024, 1024,
        nullptr, nullptr, nullptr, nullptr, nullptr, nullptr, nullptr, nullptr);
    // 4) R = relu(X @ PWT^T + EMB2[t])   [TILE=64, BK=64, K=448]
    gemm_mfma<6, 64><<<dim3(16, 256), 256, 0, stream>>>(
        X, PWT, zbias, R, BATCH, 448, 1024, 1024,
        t_in, (const float*)EMB2, nullptr, nullptr, nullptr, nullptr, nullptr, nullptr);
    // 5) loss: (R @ mlp_w2 + mlp_b2) -> scoreboard -> linear-space loss (BK=64)
    gemm_mfma<4, 64><<<dim3(7, 256), 256, 0, stream>>>(
        R, w2t, mlp_b2, nullptr, BATCH, 1024, 400, 0,
        nullptr, ltbl, x_cat, t_in, hot, noise, sched, acc);
    // 6) finalize
    finalize_kernel<<<1, 1, 0, stream>>>(acc, sched, out);
}

// Round 15
// 234.563 us; speedup vs baseline: 1.3014x; 1.0233x over previous
//
#include <hip/hip_runtime.h>
#include <hip/hip_bf16.h>
#include <math.h>

#define BATCH 16384
#define NCAT 24

// log(1e-30f), log(16)
#define L30F  (-69.07755279f)
#define LOGKF (2.7725887f)

typedef __attribute__((ext_vector_type(8))) short short8;
typedef __attribute__((ext_vector_type(4))) float f32x4;

__device__ __forceinline__ float lae(float a, float b) {
    float m = fmaxf(a, b);
    return m + logf(expf(a - m) + expf(b - m));
}

__device__ __forceinline__ void glds16(const void* g, void* l) {
    __builtin_amdgcn_global_load_lds((const __attribute__((address_space(1))) void*)g,
                                     (__attribute__((address_space(3))) void*)l,
                                     16, 0, 0);
}

// ------------------------------- fused setup (one launch) --------------------
// [0,2560): transposes {te_w1->tw1t, mlp_w1->w1t, mlp_w2->w2t} f32->bf16 [Npad x 1024]
// [2560,2784): pjb  = bf16(proj_w)  [448 x 1024], rows >= 400 zero
// [2784,3296): tw2b = bf16(te_w2)   [1024 x 1024] (no transpose)
// [3296,7296): E0 bf16 timestep-embedding table (1000x1024)
// [7296,7300): colconst[j] = te_b2[j]+proj_b[j]+L30F*sum proj_w[16:400][j]; zbias=0
// 7300: schedules + per-t loss table + acc zero
__global__ __launch_bounds__(256) void setup_all(
    const float* __restrict__ te_w1, const float* __restrict__ mlp_w1,
    const float* __restrict__ mlp_w2, const float* __restrict__ te_w2,
    __hip_bfloat16* __restrict__ tw1t, __hip_bfloat16* __restrict__ w1t,
    __hip_bfloat16* __restrict__ w2t,
    __hip_bfloat16* __restrict__ pjb, __hip_bfloat16* __restrict__ tw2b,
    __hip_bfloat16* __restrict__ E0, const float* __restrict__ proj_w,
    const float* __restrict__ proj_b, const float* __restrict__ te_b2,
    float* __restrict__ colconst, float* __restrict__ zbias,
    float* __restrict__ sched, float* __restrict__ ltbl,
    double* __restrict__ acc) {
    const int bid = blockIdx.x, tid = threadIdx.x;
    if (bid < 2560) {
        // transpose: W[K x Nw] f32 -> Wt[Npad x 1024] bf16 (zero pad)
        const int boff[4] = {0, 1024, 2048, 2560};
        const int nxs[3]  = {32, 32, 16};
        const int Nws[3]  = {1024, 1024, 400};
        const int Nps[3]  = {1024, 1024, 512};
        int job = 0;
#pragma unroll
        for (int j = 1; j < 3; ++j) job += (bid >= boff[j]) ? 1 : 0;
        const float* W = (job == 0) ? te_w1 : (job == 1) ? mlp_w1 : mlp_w2;
        __hip_bfloat16* Wt = (job == 0) ? tw1t : (job == 1) ? w1t : w2t;
        const int lb = bid - boff[job];
        const int Nw = Nws[job], Npad = Nps[job];
        const int n0 = (lb % nxs[job]) * 32, k0 = (lb / nxs[job]) * 32;
        __shared__ float t[32][33];
        int c = tid & 31, r8 = tid >> 5;
#pragma unroll
        for (int i = 0; i < 32; i += 8) {
            int k = k0 + r8 + i, n = n0 + c;
            t[r8 + i][c] = (n < Nw) ? W[(size_t)k * Nw + n] : 0.0f;
        }
        __syncthreads();
#pragma unroll
        for (int i = 0; i < 32; i += 8) {
            int n = n0 + r8 + i, k = k0 + c;
            if (n < Npad) Wt[(size_t)n * 1024 + k] = __float2bfloat16(t[c][r8 + i]);
        }
    } else if (bid < 2784) {
        int idx = (bid - 2560) * 2048 + tid * 8;
        int r = idx >> 10;
        __hip_bfloat16 v[8];
        if (r < 400) {
            const float* src = proj_w + idx;
#pragma unroll
            for (int q = 0; q < 8; ++q) v[q] = __float2bfloat16(src[q]);
        } else {
#pragma unroll
            for (int q = 0; q < 8; ++q) v[q] = __float2bfloat16(0.0f);
        }
        *(short8*)(pjb + idx) = *(const short8*)v;
    } else if (bid < 3296) {
        int idx = (bid - 2784) * 2048 + tid * 8;
        const float* src = te_w2 + idx;
        __hip_bfloat16 v[8];
#pragma unroll
        for (int q = 0; q < 8; ++q) v[q] = __float2bfloat16(src[q]);
        *(short8*)(tw2b + idx) = *(const short8*)v;
    } else if (bid < 7296) {
        int gid = (bid - 3296) * 256 + tid;
        int t = gid >> 10, j = gid & 1023;
        int jj = (j < 512) ? j : j - 512;
        float freq = expf(-logf(10000.0f) * (float)jj / 512.0f);
        float arg = (float)t * freq;
        E0[gid] = __float2bfloat16((j < 512) ? cosf(arg) : sinf(arg));
    } else if (bid < 7300) {
        int j = (bid - 7296) * 256 + tid;
        float s = 0.0f;
        for (int r = 16; r < 400; ++r) s += proj_w[(size_t)r * 1024 + j];
        colconst[j] = te_b2[j] + proj_b[j] + L30F * s;
        zbias[j] = 0.0f;
    } else {
        __shared__ double la_s[1000];
        __shared__ double lca_s[1000];
        const double PI = 3.14159265358979323846;
        for (int i = tid; i < 1000; i += 256) {
            double u0 = ((double)i / 1000.0 + 0.008) / 1.008 * PI * 0.5;
            double u1 = ((double)(i + 1) / 1000.0 + 0.008) / 1.008 * PI * 0.5;
            double c0 = cos(u0), c1 = cos(u1);
            double beta = 1.0 - (c1 * c1) / (c0 * c0);
            if (beta > 0.999) beta = 0.999;
            la_s[i] = log(1.0 - beta);
        }
        __syncthreads();
        if (tid == 0) {
            double run = 0.0;
            for (int i = 0; i < 1000; ++i) { run += la_s[i]; lca_s[i] = run; }
            *acc = 0.0;
        }
        __syncthreads();
        for (int i = tid; i < 1000; i += 256) {
            double la = la_s[i], lca = lca_s[i];
            sched[i]        = (float)la;
            sched[1000 + i] = (float)log(1.0 - exp(la) + 1e-40);
            sched[2000 + i] = (float)lca;
            sched[3000 + i] = (float)log(1.0 - exp(lca) + 1e-40);
            sched[4000 + i] = (float)sqrt(exp(lca));
            sched[5000 + i] = (float)sqrt(1.0 - exp(lca));
            // per-t loss table: {A1, B1, B1p, Qh, Qo, C0 (xc!=s), C1 (xc==s), 0}
            double alpha = exp(la);
            double A1, B1;
            if (i == 0) { A1 = 1.0; B1 = 0.0; }
            else { double ab = exp(lca_s[i - 1]); A1 = ab; B1 = (1.0 - ab) / 16.0; }
            double B1p = 1e-30 * A1 + B1;
            double Qh = alpha + (1.0 - alpha) / 16.0;
            double Qo = 1e-30 * alpha + (1.0 - alpha) / 16.0;
            double C0 = 0.0, C1 = 0.0;
            if (i > 0) {
                double UTh1 = (A1 + B1) * Qh, UTo = B1p * Qo, UTs = B1p * Qh;
                double ST1 = UTh1 + 15.0 * UTo;
                double p1 = UTh1 / ST1, p0 = UTo / ST1;
                C1 = p1 * log(p1) + 15.0 * p0 * log(p0);
                double UTh0 = (A1 + B1) * Qo;
                double ST0 = UTh0 + UTs + 14.0 * UTo;
                double pxc = UTh0 / ST0, ps = UTs / ST0, po = UTo / ST0;
                C0 = pxc * log(pxc) + ps * log(ps) + 14.0 * po * log(po);
            }
            ltbl[i * 8 + 0] = (float)A1;
            ltbl[i * 8 + 1] = (float)B1;
            ltbl[i * 8 + 2] = (float)B1p;
            ltbl[i * 8 + 3] = (float)Qh;
            ltbl[i * 8 + 4] = (float)Qo;
            ltbl[i * 8 + 5] = (float)C0;
            ltbl[i * 8 + 6] = (float)C1;
            ltbl[i * 8 + 7] = 0.0f;
        }
    }
}

// ------------------ runtime-epi 64-tile GEMM body (used by mid_all) ----------
// C[M,Nreal] = (silu?)(A @ Bt^T + bias), bf16 out. BK=32, 4 waves 2x2, 2x2 frags.
__device__ __forceinline__ void gemm64_body(
    bool silu, const __hip_bfloat16* A, const __hip_bfloat16* Bt,
    const float* bias, __hip_bfloat16* C, int M, int Kd, int Nreal,
    int Cstride, int mb, int nb, char* smem, int tid) {
    __hip_bfloat16* As = (__hip_bfloat16*)smem;
    __hip_bfloat16* Bs = As + 64 * 32;
    const int lane = tid & 63, wave = tid >> 6;
    const int wm = wave >> 1, wn = wave & 1;
    const int m0 = mb * 64, n0 = nb * 64;

    const __hip_bfloat16* gsrc[2];
    char* ldst[2];
#pragma unroll
    for (int ii = 0; ii < 2; ++ii) {
        int gc = wave * 2 + ii;
        int mat = gc >> 2, rem = gc & 3;
        int row = rem * 16 + (lane >> 2);
        int col = (lane & 3) * 8;
        if (mat == 0) {
            int r = m0 + row; if (r > M - 1) r = M - 1;
            gsrc[ii] = A + (size_t)r * Kd + col;
            ldst[ii] = (char*)As + rem * 1024;
        } else {
            int r = n0 + row;
            gsrc[ii] = Bt + (size_t)r * Kd + col;
            ldst[ii] = (char*)Bs + rem * 1024;
        }
    }
    f32x4 acc[2][2] = {};
    const int q8 = (lane >> 4) * 8;
    const int l15 = lane & 15;
    for (int k0 = 0; k0 < Kd; k0 += 32) {
        glds16(gsrc[0] + k0, ldst[0]);
        glds16(gsrc[1] + k0, ldst[1]);
        __syncthreads();
        short8 af[2], bfr[2];
#pragma unroll
        for (int i = 0; i < 2; ++i) {
            af[i]  = *(const short8*)(As + (size_t)(wm * 32 + i * 16 + l15) * 32 + q8);
            bfr[i] = *(const short8*)(Bs + (size_t)(wn * 32 + i * 16 + l15) * 32 + q8);
        }
#pragma unroll
        for (int i = 0; i < 2; ++i)
#pragma unroll
            for (int j = 0; j < 2; ++j)
                acc[i][j] = __builtin_amdgcn_mfma_f32_16x16x32_bf16(
                    af[i], bfr[j], acc[i][j], 0, 0, 0);
        __syncthreads();
    }
#pragma unroll
    for (int i = 0; i < 2; ++i) {
        int mbase = m0 + wm * 32 + i * 16 + (lane >> 4) * 4;
#pragma unroll
        for (int j = 0; j < 2; ++j) {
            int n = n0 + wn * 32 + j * 16 + l15;
            if (n >= Nreal) continue;
            float bv = bias[n];
#pragma unroll
            for (int r = 0; r < 4; ++r) {
                int m = mbase + r;
                if (m >= M) continue;
                float v = acc[i][j][r] + bv;
                if (silu) v = v / (1.0f + expf(-v));
                C[(size_t)m * Cstride + n] = __float2bfloat16(v);
            }
        }
    }
}

// ------------------- mid: bias2 + PWT + E1 + W12t + prep_x (one launch) ------
// [0,16): bias2[k] = dot(w1t_row_k, colconst) + mlp_b1[k]   (64 k's per block)
// [16,128): PWT [1024x448]  [128,384): E1   [384,640): W12t   [640,1664): prep_x
__global__ __launch_bounds__(256) void mid_all(
    const float* __restrict__ x_num, const int* __restrict__ x_cat,
    const int* __restrict__ t_in, const float* __restrict__ noise,
    const float* __restrict__ gum, const float* __restrict__ sched,
    __hip_bfloat16* __restrict__ X, int* __restrict__ hot,
    const __hip_bfloat16* __restrict__ w1t, const __hip_bfloat16* __restrict__ pjb,
    const __hip_bfloat16* __restrict__ tw2b, const __hip_bfloat16* __restrict__ E0,
    const __hip_bfloat16* __restrict__ tw1t,
    const float* __restrict__ te_b1, const float* __restrict__ zbias,
    __hip_bfloat16* __restrict__ PWT, __hip_bfloat16* __restrict__ E1,
    __hip_bfloat16* __restrict__ W12t,
    const float* __restrict__ colconst, const float* __restrict__ mlp_b1,
    float* __restrict__ bias2) {
    __shared__ __align__(16) char SM[8192];
    const int bid = blockIdx.x, tid = threadIdx.x;
    if (bid < 16) {
        // ---- bias2: per wave, 16 k's; per k: 64-lane dot over 1024 elements
        const int lane = tid & 63, wave = tid >> 6;
        for (int kk = 0; kk < 16; ++kk) {
            int k = bid * 64 + wave * 16 + kk;
            const __hip_bfloat16* row = w1t + (size_t)k * 1024 + lane * 16;
            const float* cc = colconst + lane * 16;
            float s = 0.0f;
#pragma unroll
            for (int q = 0; q < 16; ++q)
                s = fmaf(__bfloat162float(row[q]), cc[q], s);
            for (int off = 32; off > 0; off >>= 1)
                s += __shfl_down(s, off);
            if (lane == 0) bias2[k] = s + mlp_b1[k];
        }
    } else if (bid < 128) {
        // ---- PWT[j,k] = sum_n w1[n,j] proj_w[k,n] -> [1024 x 448] (cols 416+ = 0)
        int lb = bid - 16;
        gemm64_body(false, w1t, pjb, zbias, PWT, 1024, 1024, 448, 448,
                    lb / 7, lb % 7, SM, tid);
    } else if (bid < 384) {
        // ---- E1 = silu(E0 @ te_w1 + te_b1)  [1000 x 1024]
        int lb = bid - 128;
        gemm64_body(true, E0, tw1t, te_b1, E1, 1000, 1024, 1024, 1024,
                    lb >> 4, lb & 15, SM, tid);
    } else if (bid < 640) {
        // ---- W12t[k,n] = sum_j w1[j,k] te_w2[n,j]  ( = (te_w2@w1)^T )
        int lb = bid - 384;
        gemm64_body(false, w1t, tw2b, zbias, W12t, 1024, 1024, 1024, 1024,
                    lb >> 4, lb & 15, SM, tid);
    } else {
        // ---- prep_x: gumbel argmax + build X[B x 448] bf16 (cols 416+ = 0)
        float* xnt = (float*)SM;                    // [16][16]
        int* sh_hot = (int*)(SM + 1024);            // [16][24]
        int* sh_t = (int*)(SM + 1024 + 1536);       // [16]
        const int b0 = (bid - 640) * 16;
        const float* LOG_CA = sched + 2000;
        const float* LOG_1M_CA = sched + 3000;
        const float* SQ_AC = sched + 4000;
        const float* SQ_1M = sched + 5000;
        if (tid < 16) sh_t[tid] = t_in[b0 + tid];
        __syncthreads();
        {
            int r = tid >> 4, i = tid & 15;
            int t = sh_t[r];
            xnt[r * 16 + i] = SQ_AC[t] * x_num[(size_t)(b0 + r) * 16 + i] +
                              SQ_1M[t] * noise[(size_t)(b0 + r) * 16 + i];
        }
        for (int task = tid; task < 16 * 24; task += 256) {
            int r = task / 24, c = task - r * 24;
            int t = sh_t[r];
            int xc = x_cat[(size_t)(b0 + r) * 24 + c];
            float l1 = LOG_1M_CA[t] - LOGKF;
            float lca = LOG_CA[t];
            float vh = lae(lca, l1);
            float vo = lae(L30F + lca, l1);
            const float* gu = gum + (size_t)(b0 + r) * 384 + c * 16;
            float best = -3.0e38f;
            int bi = 0;
#pragma unroll
            for (int k = 0; k < 16; ++k) {
                float g = -logf(-logf(gu[k] + 1e-30f) + 1e-30f);
                float v = g + ((k == xc) ? vh : vo);
                if (v > best) { best = v; bi = k; }
            }
            sh_hot[r * 24 + c] = bi;
            hot[(size_t)(b0 + r) * 24 + c] = bi;
        }
        __syncthreads();
        const float DELTA = 69.07755279f;  // -L30F
#pragma unroll
        for (int it = 0; it < 4; ++it) {
            int idx = it * 256 + tid;          // 16*56 = 896 short8 stores
            if (idx < 896) {
                int r = idx / 56, jc = idx - r * 56;
                int j0 = jc * 8;
                __hip_bfloat16 v[8];
#pragma unroll
                for (int qq = 0; qq < 8; ++qq) {
                    int j = j0 + qq;
                    float f = 0.0f;
                    if (j < 16) {
                        f = xnt[r * 16 + j];
                    } else if (j < 400) {
                        int c = (j - 16) >> 4, k = (j - 16) & 15;
                        f = (sh_hot[r * 24 + c] == k) ? DELTA : 0.0f;
                    }
                    v[qq] = __float2bfloat16(f);
                }
                *(short8*)(X + (size_t)(b0 + r) * 448 + j0) = *(const short8*)v;
            }
        }
    }
}

// ------------------------------------------------------------ bf16 MFMA GEMM
// EPI: 5 = plain bf16 store (BK=32),
// 6 = +embrow[t[m]][n] (bf16 table, LDS-gathered via batched glds16) + relu + bf16
//     (BK=64).
template <int EPI, int TILE>
__global__ __launch_bounds__(256) void gemm_mfma(
    const __hip_bfloat16* __restrict__ A, const __hip_bfloat16* __restrict__ Bt,
    const float* __restrict__ bias, void* __restrict__ Cout,
    int M, int Kd, int Nreal, int Cstride,
    const int* __restrict__ tidx, const float* __restrict__ rowbias) {
    constexpr int FM  = TILE / 32;      // MFMA frags per wave per dim
    constexpr int BK  = (EPI == 6) ? 64 : 32;
    constexpr int KCH = BK / 32;        // 32-wide k-halves per K-iter
    constexpr int RCH = TILE / 16;      // 16-row chunks per matrix per half
    constexpr int CPM2 = RCH * KCH;     // chunks per matrix
    constexpr int CPW2 = CPM2 / 2;      // chunks per wave (4 waves, 2 matrices)
    constexpr int STAGE = 4 * KCH * TILE * 32;   // As+Bs bytes
    constexpr int SMEM_BYTES = (EPI == 6) ? (STAGE + TILE * TILE * 2) : STAGE;
    __shared__ __align__(16) char SMEM[SMEM_BYTES];
    __hip_bfloat16* As = (__hip_bfloat16*)SMEM;            // [KCH][TILE][32]
    __hip_bfloat16* Bs = As + KCH * TILE * 32;

    const int tid = threadIdx.x;
    const int lane = tid & 63, wave = tid >> 6;
    const int wm = wave >> 1, wn = wave & 1;

    // XCD swizzle (same-m n-blocks consecutive within one XCD)
    int mb, nb;
    {
        int nbx = gridDim.x, nby = gridDim.y;
        int b = blockIdx.y * nbx + blockIdx.x;
        if ((nby & 7) == 0) {
            int x = b & 7, g = b >> 3;
            nb = g % nbx;
            mb = x + 8 * (g / nbx);
        } else { mb = blockIdx.y; nb = blockIdx.x; }
    }
    const int m0 = mb * TILE, n0 = nb * TILE;

    const __hip_bfloat16* gsrc[CPW2];
    char* ldst[CPW2];
#pragma unroll
    for (int ii = 0; ii < CPW2; ++ii) {
        int gc = wave * CPW2 + ii;
        int mat = gc / CPM2, rem = gc % CPM2;
        int h = rem / RCH, rc = rem % RCH;
        int row = rc * 16 + (lane >> 2);
        int col = h * 32 + (lane & 3) * 8;
        size_t loff = ((size_t)h * TILE * 32 + (size_t)rc * 16 * 32) * 2;
        if (mat == 0) {
            int r = m0 + row; if (r > M - 1) r = M - 1;
            gsrc[ii] = A + (size_t)r * Kd + col;
            ldst[ii] = (char*)As + loff;
        } else {
            int r = n0 + row;
            gsrc[ii] = Bt + (size_t)r * Kd + col;
            ldst[ii] = (char*)Bs + loff;
        }
    }

    // EPI==6: gather the block's TILE rowbias rows (bf16, TILE*2 B each) into
    // LDS via batched glds16 (per-lane global addr, wave-uniform LDS base).
    if (EPI == 6) {
        char* LE = SMEM + STAGE;
        const __hip_bfloat16* embp = (const __hip_bfloat16*)rowbias;
        if (TILE == 128) {
            int tvec = tidx[m0 + wave * 32 + (lane & 31)];
#pragma unroll
            for (int b = 0; b < 8; ++b) {
                int trow = __shfl(tvec, b * 4 + (lane >> 4));
                glds16((const char*)(embp + (size_t)trow * 1024 + n0) + (lane & 15) * 16,
                       LE + (wave * 32 + b * 4) * 256);
            }
        } else {  // TILE == 64: rows are 128 B = 8 lanes x 16 B
            int tvec = tidx[m0 + wave * 16 + (lane & 15)];
#pragma unroll
            for (int b = 0; b < 2; ++b) {
                int trow = __shfl(tvec, b * 8 + (lane >> 3));
                glds16((const char*)(embp + (size_t)trow * 1024 + n0) + (lane & 7) * 16,
                       LE + (wave * 16 + b * 8) * 128);
            }
        }
    }

    f32x4 acc[FM][FM] = {};
    const int q8 = (lane >> 4) * 8;
    const int l15 = lane & 15;

    for (int k0 = 0; k0 < Kd; k0 += BK) {
#pragma unroll
        for (int ii = 0; ii < CPW2; ++ii) glds16(gsrc[ii] + k0, ldst[ii]);
        __syncthreads();
#pragma unroll
        for (int kk = 0; kk < KCH; ++kk) {
            short8 af[FM], bfr[FM];
#pragma unroll
            for (int i = 0; i < FM; ++i) {
                af[i]  = *(const short8*)(As + (size_t)kk * TILE * 32 +
                                          (size_t)(wm * (TILE / 2) + i * 16 + l15) * 32 + q8);
                bfr[i] = *(const short8*)(Bs + (size_t)kk * TILE * 32 +
                                          (size_t)(wn * (TILE / 2) + i * 16 + l15) * 32 + q8);
            }
#pragma unroll
            for (int i = 0; i < FM; ++i)
#pragma unroll
                for (int j = 0; j < FM; ++j)
                    acc[i][j] = __builtin_amdgcn_mfma_f32_16x16x32_bf16(
                        af[i], bfr[j], acc[i][j], 0, 0, 0);
        }
        __syncthreads();
    }

    const __hip_bfloat16* LE = (const __hip_bfloat16*)(SMEM + STAGE);
#pragma unroll
    for (int i = 0; i < FM; ++i) {
        int mlbase = wm * (TILE / 2) + i * 16 + (lane >> 4) * 4;
#pragma unroll
        for (int j = 0; j < FM; ++j) {
            int nl = wn * (TILE / 2) + j * 16 + l15;
            int n = n0 + nl;
            if (n >= Nreal) continue;
            float bv = bias[n];
#pragma unroll
            for (int r = 0; r < 4; ++r) {
                int ml = mlbase + r;
                int m = m0 + ml;
                if (m >= M) continue;
                float v = acc[i][j][r] + bv;
                if (EPI == 6) { v += __bfloat162float(LE[ml * TILE + nl]); v = fmaxf(v, 0.0f); }
                ((__hip_bfloat16*)Cout)[(size_t)m * Cstride + n] = __float2bfloat16(v);
            }
        }
    }
}

// --------------------- fused loss GEMM: 128x64 tile, BK=64 -------------------
// (R[M,1024] @ w2t^T + mlp_b2) -> LDS scoreboard S[128][64] -> per-(row,cat)
// linear-space loss -> atomicAdd. grid dim3(7, 128). ltbl = per-t loss table.
__global__ __launch_bounds__(256) void gemm_loss(
    const __hip_bfloat16* __restrict__ A, const __hip_bfloat16* __restrict__ Bt,
    const float* __restrict__ bias, int M, int Kd,
    const float* __restrict__ ltbl,
    const int* __restrict__ x_cat, const int* __restrict__ t_in,
    const int* __restrict__ hot, const float* __restrict__ noise,
    double* __restrict__ acc_out) {
    constexpr int TM = 128, TN = 64, BK = 64;
    constexpr int KCH = BK / 32;                 // 2
    constexpr int CPMA = KCH * (TM / 16);        // 16 A chunks
    constexpr int CPMB = KCH * (TN / 16);        // 8 B chunks
    constexpr int CPW = (CPMA + CPMB) / 4;       // 6 per wave
    constexpr int STAGE = (TM + TN) * BK * 2;    // 24576 B
    constexpr int SCORE = TM * TN * 4;           // 32768 B
    __shared__ __align__(16) char SMEM[SCORE > STAGE ? SCORE : STAGE];
    __hip_bfloat16* As = (__hip_bfloat16*)SMEM;          // [KCH][TM][32]
    __hip_bfloat16* Bs = As + KCH * TM * 32;             // [KCH][TN][32]

    const int tid = threadIdx.x;
    const int lane = tid & 63, wave = tid >> 6;
    const int wm = wave >> 1, wn = wave & 1;             // wave tile 64x32

    // XCD swizzle
    int mb, nb;
    {
        int nbx = gridDim.x;
        int b = blockIdx.y * nbx + blockIdx.x;
        int x = b & 7, g = b >> 3;
        nb = g % nbx;
        mb = x + 8 * (g / nbx);
    }
    const int m0 = mb * TM, n0 = nb * TN;

    const __hip_bfloat16* gsrc[CPW];
    char* ldst[CPW];
#pragma unroll
    for (int ii = 0; ii < CPW; ++ii) {
        int gc = wave * CPW + ii;
        int row, col;
        if (gc < CPMA) {
            int h = gc / (TM / 16), rc = gc % (TM / 16);
            row = rc * 16 + (lane >> 2);
            col = h * 32 + (lane & 3) * 8;
            gsrc[ii] = A + (size_t)(m0 + row) * Kd + col;
            ldst[ii] = (char*)As + ((size_t)h * TM * 32 + (size_t)rc * 16 * 32) * 2;
        } else {
            int rem = gc - CPMA;
            int h = rem / (TN / 16), rc = rem % (TN / 16);
            row = rc * 16 + (lane >> 2);
            col = h * 32 + (lane & 3) * 8;
            gsrc[ii] = Bt + (size_t)(n0 + row) * Kd + col;
            ldst[ii] = (char*)Bs + ((size_t)h * TN * 32 + (size_t)rc * 16 * 32) * 2;
        }
    }

    f32x4 acc[4][2] = {};
    const int q8 = (lane >> 4) * 8;
    const int l15 = lane & 15;

    for (int k0 = 0; k0 < Kd; k0 += BK) {
#pragma unroll
        for (int ii = 0; ii < CPW; ++ii) glds16(gsrc[ii] + k0, ldst[ii]);
        __syncthreads();
#pragma unroll
        for (int kk = 0; kk < KCH; ++kk) {
            short8 af[4], bfr[2];
#pragma unroll
            for (int i = 0; i < 4; ++i)
                af[i] = *(const short8*)(As + (size_t)kk * TM * 32 +
                                         (size_t)(wm * 64 + i * 16 + l15) * 32 + q8);
#pragma unroll
            for (int j = 0; j < 2; ++j)
                bfr[j] = *(const short8*)(Bs + (size_t)kk * TN * 32 +
                                          (size_t)(wn * 32 + j * 16 + l15) * 32 + q8);
#pragma unroll
            for (int i = 0; i < 4; ++i)
#pragma unroll
                for (int j = 0; j < 2; ++j)
                    acc[i][j] = __builtin_amdgcn_mfma_f32_16x16x32_bf16(
                        af[i], bfr[j], acc[i][j], 0, 0, 0);
        }
        __syncthreads();
    }

    // Phase 1: dump acc to scoreboard S[128][64], swizzle col' = (col+row)&63.
    float* S = (float*)SMEM;
#pragma unroll
    for (int i = 0; i < 4; ++i) {
        int rbase = wm * 64 + i * 16 + (lane >> 4) * 4;
#pragma unroll
        for (int j = 0; j < 2; ++j) {
            int lcol = wn * 32 + j * 16 + l15;
#pragma unroll
            for (int r = 0; r < 4; ++r) {
                int row = rbase + r;
                S[row * TN + ((lcol + row) & (TN - 1))] = acc[i][j][r];
            }
        }
    }
    __syncthreads();

    // Phase 2: one (row, 16-col-group) pair per thread iter (512 pairs).
    double local = 0.0;
    for (int p = tid; p < TM * (TN / 16); p += 256) {
        int ml = p & (TM - 1), cg = p / TM;
        int colbase = n0 + cg * 16;
        if (colbase >= 400) continue;
        int m = m0 + ml;
        float ocv[16];
#pragma unroll
        for (int k = 0; k < 16; ++k)
            ocv[k] = S[ml * TN + ((cg * 16 + k + ml) & (TN - 1))] + bias[colbase + k];
        if (colbase == 0) {
#pragma unroll
            for (int k = 0; k < 16; ++k) {
                float d = noise[(size_t)m * 16 + k] - ocv[k];
                local += (double)(d * d) * (1.0 / (16.0 * BATCH));
            }
        } else {
            int c = (colbase - 16) >> 4;
            int t = t_in[m];
            int xc = x_cat[m * 24 + c];
            int s = hot[m * 24 + c];
            const float* tb = ltbl + t * 8;
            float A1 = tb[0], B1 = tb[1], B1p = tb[2], Qh = tb[3], Qo = tb[4];
            float mx = -3e38f;
#pragma unroll
            for (int k = 0; k < 16; ++k) mx = fmaxf(mx, ocv[k]);
            float E[16];
            float sm = 0.0f;
#pragma unroll
            for (int k = 0; k < 16; ++k) { E[k] = expf(ocv[k] - mx); sm += E[k]; }
            float A1s = A1 / sm;
            float SU = 0.0f, slU = 0.0f, lUxc = 0.0f, lUs = 0.0f;
#pragma unroll
            for (int k = 0; k < 16; ++k) {
                float U = (E[k] * A1s + B1) * ((k == s) ? Qh : Qo);
                SU += U;
                float l = logf(fmaxf(U, 1e-37f));
                slU += l;
                if (k == xc) lUxc = l;
                if (k == s)  lUs = l;
            }
            float lSU = logf(SU);
            float Wh, Ws, Wo, C;
            if (t == 0) {
                Wh = 1.0f; Ws = 1e-30f; Wo = 1e-30f; C = 0.0f;
            } else {
                int e = (xc == s);
                float UTh = (A1 + B1) * (e ? Qh : Qo);
                float UTs = B1p * Qh;
                float UTo = B1p * Qo;
                float ST = e ? (UTh + 15.0f * UTo) : (UTh + UTs + 14.0f * UTo);
                float rST = 1.0f / ST;
                Wh = UTh * rST; Wo = UTo * rST; Ws = UTs * rST;
                C = e ? tb[6] : tb[5];
            }
            float wsTerm = (xc == s) ? 0.0f : (Ws - Wo);
            float SPU = Wo * slU + (Wh - Wo) * lUxc + wsTerm * lUs;
            float Lt = C - SPU + lSU;
            local += (double)Lt * (1.0 / (24.0 * BATCH));
        }
    }
    for (int off = 32; off > 0; off >>= 1)
        local += __shfl_down(local, off);
    __syncthreads();
    double* wred = (double*)SMEM;
    if (lane == 0) wred[wave] = local;
    __syncthreads();
    if (tid == 0)
        atomicAdd(acc_out, wred[0] + wred[1] + wred[2] + wred[3]);
}

__global__ void finalize_kernel(const double* __restrict__ acc,
                                const float* __restrict__ sched,
                                float* __restrict__ out) {
    // kl_prior is identical for every (sample, category): add once.
    float lcaT = sched[2999];
    float l1mT = sched[3999] - LOGKF;
    float ph = lae(lcaT, l1mT);
    float po = lae(L30F + lcaT, l1mT);
    float prior = expf(ph) * (ph + LOGKF) + 15.0f * expf(po) * (po + LOGKF);
    out[0] = (float)(*acc + (double)prior);
}

extern "C" void kernel_launch(void* const* d_in, const int* in_sizes, int n_in,
                              void* d_out, int out_size, void* d_ws, size_t ws_size,
                              hipStream_t stream) {
    const float* x_num  = (const float*)d_in[0];
    const int*   x_cat  = (const int*)d_in[1];
    const int*   t_in   = (const int*)d_in[2];
    const float* noise  = (const float*)d_in[3];
    const float* gum    = (const float*)d_in[4];
    const float* te_w1  = (const float*)d_in[5];
    const float* te_b1  = (const float*)d_in[6];
    const float* te_w2  = (const float*)d_in[7];
    const float* te_b2  = (const float*)d_in[8];
    const float* proj_w = (const float*)d_in[9];
    const float* proj_b = (const float*)d_in[10];
    const float* mlp_w1 = (const float*)d_in[11];
    const float* mlp_b1 = (const float*)d_in[12];
    const float* mlp_w2 = (const float*)d_in[13];
    const float* mlp_b2 = (const float*)d_in[14];
    float* out = (float*)d_out;

    char* w = (char*)d_ws;
    size_t off = 0;
    auto alloc = [&](size_t bytes) {
        void* p = w + off;
        off += (bytes + 1023) & ~(size_t)1023;
        return p;
    };
    double* acc     = (double*)alloc(1024);
    float* sched    = (float*)alloc(6 * 1000 * 4);
    float* ltbl     = (float*)alloc(8 * 1000 * 4);
    int*   hot      = (int*)alloc((size_t)BATCH * 24 * 4);
    float* colconst = (float*)alloc(1024 * 4);
    float* zbias    = (float*)alloc(1024 * 4);
    float* bias2    = (float*)alloc(1024 * 4);
    __hip_bfloat16* E0    = (__hip_bfloat16*)alloc((size_t)1024 * 1024 * 2);
    __hip_bfloat16* E1    = (__hip_bfloat16*)alloc((size_t)1024 * 1024 * 2);
    __hip_bfloat16* EMB2  = (__hip_bfloat16*)alloc((size_t)1024 * 1024 * 2);
    __hip_bfloat16* tw1t  = (__hip_bfloat16*)alloc((size_t)1024 * 1024 * 2);
    __hip_bfloat16* tw2b  = (__hip_bfloat16*)alloc((size_t)1024 * 1024 * 2);
    __hip_bfloat16* W12t  = (__hip_bfloat16*)alloc((size_t)1024 * 1024 * 2);
    __hip_bfloat16* w1t   = (__hip_bfloat16*)alloc((size_t)1024 * 1024 * 2);
    __hip_bfloat16* w2t   = (__hip_bfloat16*)alloc((size_t)512 * 1024 * 2);
    __hip_bfloat16* pjb   = (__hip_bfloat16*)alloc((size_t)448 * 1024 * 2);
    __hip_bfloat16* PWT   = (__hip_bfloat16*)alloc((size_t)1024 * 448 * 2);
    __hip_bfloat16* X     = (__hip_bfloat16*)alloc((size_t)BATCH * 448 * 2);
    __hip_bfloat16* R     = (__hip_bfloat16*)alloc((size_t)BATCH * 1024 * 2);

    // 1) setup: transposes + casts + E0 + colconst + schedules/ltbl + acc zero
    setup_all<<<7301, 256, 0, stream>>>(te_w1, mlp_w1, mlp_w2, te_w2,
                                        tw1t, w1t, w2t, pjb, tw2b,
                                        E0, proj_w, proj_b, te_b2,
                                        colconst, zbias, sched, ltbl, acc);
    // 2) mid: bias2 + PWT + E1 + W12t + prep_x
    mid_all<<<1664, 256, 0, stream>>>(x_num, x_cat, t_in, noise, gum, sched, X, hot,
                                      w1t, pjb, tw2b, E0, tw1t, te_b1, zbias,
                                      PWT, E1, W12t, colconst, mlp_b1, bias2);
    // 3) EMB2 = E1 @ W12t^T + bias2   [per-t hidden-layer bias table]
    gemm_mfma<5, 64><<<dim3(16, 16), 256, 0, stream>>>(
        E1, W12t, bias2, EMB2, 1000, 1024, 1024, 1024, nullptr, nullptr);
    // 4) R = relu(X @ PWT^T + EMB2[t])   [TILE=64, BK=64, K=448]
    gemm_mfma<6, 64><<<dim3(16, 256), 256, 0, stream>>>(
        X, PWT, zbias, R, BATCH, 448, 1024, 1024,
        t_in, (const float*)EMB2);
    // 5) loss: 128x64 tile, BK=64 -> scoreboard -> linear-space loss
    gemm_loss<<<dim3(7, 128), 256, 0, stream>>>(
        R, w2t, mlp_b2, BATCH, 1024, ltbl, x_cat, t_in, hot, noise, acc);
    // 6) finalize
    finalize_kernel<<<1, 1, 0, stream>>>(acc, sched, out);
}

// Round 16
// 232.062 us; speedup vs baseline: 1.3154x; 1.0108x over previous
//
#include <hip/hip_runtime.h>
#include <hip/hip_bf16.h>
#include <math.h>

#define BATCH 16384
#define NCAT 24

// log(1e-30f), log(16)
#define L30F  (-69.07755279f)
#define LOGKF (2.7725887f)

typedef __attribute__((ext_vector_type(8))) short short8;
typedef __attribute__((ext_vector_type(4))) float f32x4;

__device__ __forceinline__ float lae(float a, float b) {
    float m = fmaxf(a, b);
    return m + logf(expf(a - m) + expf(b - m));
}

__device__ __forceinline__ void glds16(const void* g, void* l) {
    __builtin_amdgcn_global_load_lds((const __attribute__((address_space(1))) void*)g,
                                     (__attribute__((address_space(3))) void*)l,
                                     16, 0, 0);
}

// ------------------------------- fused setup (one launch) --------------------
// [0,2560): transposes {te_w1->tw1t, mlp_w1->w1t, mlp_w2->w2t} f32->bf16 [Npad x 1024]
// [2560,2784): pjb  = bf16(proj_w)  [448 x 1024], rows >= 400 zero
// [2784,3296): tw2b = bf16(te_w2)   [1024 x 1024] (no transpose)
// [3296,7296): E0 bf16 timestep-embedding table (1000x1024)
// [7296,7300): colconst[j] = te_b2[j]+proj_b[j]+L30F*sum proj_w[16:400][j]; zbias=0
// 7300: schedules + per-t loss table + acc zero
__global__ __launch_bounds__(256) void setup_all(
    const float* __restrict__ te_w1, const float* __restrict__ mlp_w1,
    const float* __restrict__ mlp_w2, const float* __restrict__ te_w2,
    __hip_bfloat16* __restrict__ tw1t, __hip_bfloat16* __restrict__ w1t,
    __hip_bfloat16* __restrict__ w2t,
    __hip_bfloat16* __restrict__ pjb, __hip_bfloat16* __restrict__ tw2b,
    __hip_bfloat16* __restrict__ E0, const float* __restrict__ proj_w,
    const float* __restrict__ proj_b, const float* __restrict__ te_b2,
    float* __restrict__ colconst, float* __restrict__ zbias,
    float* __restrict__ sched, float* __restrict__ ltbl,
    double* __restrict__ acc) {
    const int bid = blockIdx.x, tid = threadIdx.x;
    if (bid < 2560) {
        // transpose: W[K x Nw] f32 -> Wt[Npad x 1024] bf16 (zero pad)
        const int boff[4] = {0, 1024, 2048, 2560};
        const int nxs[3]  = {32, 32, 16};
        const int Nws[3]  = {1024, 1024, 400};
        const int Nps[3]  = {1024, 1024, 512};
        int job = 0;
#pragma unroll
        for (int j = 1; j < 3; ++j) job += (bid >= boff[j]) ? 1 : 0;
        const float* W = (job == 0) ? te_w1 : (job == 1) ? mlp_w1 : mlp_w2;
        __hip_bfloat16* Wt = (job == 0) ? tw1t : (job == 1) ? w1t : w2t;
        const int lb = bid - boff[job];
        const int Nw = Nws[job], Npad = Nps[job];
        const int n0 = (lb % nxs[job]) * 32, k0 = (lb / nxs[job]) * 32;
        __shared__ float t[32][33];
        int c = tid & 31, r8 = tid >> 5;
#pragma unroll
        for (int i = 0; i < 32; i += 8) {
            int k = k0 + r8 + i, n = n0 + c;
            t[r8 + i][c] = (n < Nw) ? W[(size_t)k * Nw + n] : 0.0f;
        }
        __syncthreads();
#pragma unroll
        for (int i = 0; i < 32; i += 8) {
            int n = n0 + r8 + i, k = k0 + c;
            if (n < Npad) Wt[(size_t)n * 1024 + k] = __float2bfloat16(t[c][r8 + i]);
        }
    } else if (bid < 2784) {
        int idx = (bid - 2560) * 2048 + tid * 8;
        int r = idx >> 10;
        __hip_bfloat16 v[8];
        if (r < 400) {
            const float* src = proj_w + idx;
#pragma unroll
            for (int q = 0; q < 8; ++q) v[q] = __float2bfloat16(src[q]);
        } else {
#pragma unroll
            for (int q = 0; q < 8; ++q) v[q] = __float2bfloat16(0.0f);
        }
        *(short8*)(pjb + idx) = *(const short8*)v;
    } else if (bid < 3296) {
        int idx = (bid - 2784) * 2048 + tid * 8;
        const float* src = te_w2 + idx;
        __hip_bfloat16 v[8];
#pragma unroll
        for (int q = 0; q < 8; ++q) v[q] = __float2bfloat16(src[q]);
        *(short8*)(tw2b + idx) = *(const short8*)v;
    } else if (bid < 7296) {
        int gid = (bid - 3296) * 256 + tid;
        int t = gid >> 10, j = gid & 1023;
        int jj = (j < 512) ? j : j - 512;
        float freq = expf(-logf(10000.0f) * (float)jj / 512.0f);
        float arg = (float)t * freq;
        E0[gid] = __float2bfloat16((j < 512) ? cosf(arg) : sinf(arg));
    } else if (bid < 7300) {
        int j = (bid - 7296) * 256 + tid;
        float s = 0.0f;
        for (int r = 16; r < 400; ++r) s += proj_w[(size_t)r * 1024 + j];
        colconst[j] = te_b2[j] + proj_b[j] + L30F * s;
        zbias[j] = 0.0f;
    } else {
        __shared__ double la_s[1000];
        __shared__ double lca_s[1000];
        const double PI = 3.14159265358979323846;
        for (int i = tid; i < 1000; i += 256) {
            double u0 = ((double)i / 1000.0 + 0.008) / 1.008 * PI * 0.5;
            double u1 = ((double)(i + 1) / 1000.0 + 0.008) / 1.008 * PI * 0.5;
            double c0 = cos(u0), c1 = cos(u1);
            double beta = 1.0 - (c1 * c1) / (c0 * c0);
            if (beta > 0.999) beta = 0.999;
            la_s[i] = log(1.0 - beta);
        }
        __syncthreads();
        if (tid == 0) {
            double run = 0.0;
            for (int i = 0; i < 1000; ++i) { run += la_s[i]; lca_s[i] = run; }
            *acc = 0.0;
        }
        __syncthreads();
        for (int i = tid; i < 1000; i += 256) {
            double la = la_s[i], lca = lca_s[i];
            sched[i]        = (float)la;
            sched[1000 + i] = (float)log(1.0 - exp(la) + 1e-40);
            sched[2000 + i] = (float)lca;
            sched[3000 + i] = (float)log(1.0 - exp(lca) + 1e-40);
            sched[4000 + i] = (float)sqrt(exp(lca));
            sched[5000 + i] = (float)sqrt(1.0 - exp(lca));
            // per-t loss table: {A1, B1, B1p, Qh, Qo, C0 (xc!=s), C1 (xc==s), 0}
            double alpha = exp(la);
            double A1, B1;
            if (i == 0) { A1 = 1.0; B1 = 0.0; }
            else { double ab = exp(lca_s[i - 1]); A1 = ab; B1 = (1.0 - ab) / 16.0; }
            double B1p = 1e-30 * A1 + B1;
            double Qh = alpha + (1.0 - alpha) / 16.0;
            double Qo = 1e-30 * alpha + (1.0 - alpha) / 16.0;
            double C0 = 0.0, C1 = 0.0;
            if (i > 0) {
                double UTh1 = (A1 + B1) * Qh, UTo = B1p * Qo, UTs = B1p * Qh;
                double ST1 = UTh1 + 15.0 * UTo;
                double p1 = UTh1 / ST1, p0 = UTo / ST1;
                C1 = p1 * log(p1) + 15.0 * p0 * log(p0);
                double UTh0 = (A1 + B1) * Qo;
                double ST0 = UTh0 + UTs + 14.0 * UTo;
                double pxc = UTh0 / ST0, ps = UTs / ST0, po = UTo / ST0;
                C0 = pxc * log(pxc) + ps * log(ps) + 14.0 * po * log(po);
            }
            ltbl[i * 8 + 0] = (float)A1;
            ltbl[i * 8 + 1] = (float)B1;
            ltbl[i * 8 + 2] = (float)B1p;
            ltbl[i * 8 + 3] = (float)Qh;
            ltbl[i * 8 + 4] = (float)Qo;
            ltbl[i * 8 + 5] = (float)C0;
            ltbl[i * 8 + 6] = (float)C1;
            ltbl[i * 8 + 7] = 0.0f;
        }
    }
}

// ------------------ runtime-epi 64-tile GEMM body (used by mid_all) ----------
// C[M,Nreal] = (silu?)(A @ Bt^T + bias), bf16 out. BK=32, 4 waves 2x2, 2x2 frags.
__device__ __forceinline__ void gemm64_body(
    bool silu, const __hip_bfloat16* A, const __hip_bfloat16* Bt,
    const float* bias, __hip_bfloat16* C, int M, int Kd, int Nreal,
    int Cstride, int mb, int nb, char* smem, int tid) {
    __hip_bfloat16* As = (__hip_bfloat16*)smem;
    __hip_bfloat16* Bs = As + 64 * 32;
    const int lane = tid & 63, wave = tid >> 6;
    const int wm = wave >> 1, wn = wave & 1;
    const int m0 = mb * 64, n0 = nb * 64;

    const __hip_bfloat16* gsrc[2];
    char* ldst[2];
#pragma unroll
    for (int ii = 0; ii < 2; ++ii) {
        int gc = wave * 2 + ii;
        int mat = gc >> 2, rem = gc & 3;
        int row = rem * 16 + (lane >> 2);
        int col = (lane & 3) * 8;
        if (mat == 0) {
            int r = m0 + row; if (r > M - 1) r = M - 1;
            gsrc[ii] = A + (size_t)r * Kd + col;
            ldst[ii] = (char*)As + rem * 1024;
        } else {
            int r = n0 + row;
            gsrc[ii] = Bt + (size_t)r * Kd + col;
            ldst[ii] = (char*)Bs + rem * 1024;
        }
    }
    f32x4 acc[2][2] = {};
    const int q8 = (lane >> 4) * 8;
    const int l15 = lane & 15;
    for (int k0 = 0; k0 < Kd; k0 += 32) {
        glds16(gsrc[0] + k0, ldst[0]);
        glds16(gsrc[1] + k0, ldst[1]);
        __syncthreads();
        short8 af[2], bfr[2];
#pragma unroll
        for (int i = 0; i < 2; ++i) {
            af[i]  = *(const short8*)(As + (size_t)(wm * 32 + i * 16 + l15) * 32 + q8);
            bfr[i] = *(const short8*)(Bs + (size_t)(wn * 32 + i * 16 + l15) * 32 + q8);
        }
#pragma unroll
        for (int i = 0; i < 2; ++i)
#pragma unroll
            for (int j = 0; j < 2; ++j)
                acc[i][j] = __builtin_amdgcn_mfma_f32_16x16x32_bf16(
                    af[i], bfr[j], acc[i][j], 0, 0, 0);
        __syncthreads();
    }
#pragma unroll
    for (int i = 0; i < 2; ++i) {
        int mbase = m0 + wm * 32 + i * 16 + (lane >> 4) * 4;
#pragma unroll
        for (int j = 0; j < 2; ++j) {
            int n = n0 + wn * 32 + j * 16 + l15;
            if (n >= Nreal) continue;
            float bv = bias[n];
#pragma unroll
            for (int r = 0; r < 4; ++r) {
                int m = mbase + r;
                if (m >= M) continue;
                float v = acc[i][j][r] + bv;
                if (silu) v = v / (1.0f + expf(-v));
                C[(size_t)m * Cstride + n] = __float2bfloat16(v);
            }
        }
    }
}

// ------------------- mid: bias2 + PWT + E1 + W12t + prep_x (one launch) ------
// [0,16): bias2[k] = dot(w1t_row_k, colconst) + mlp_b1[k]   (64 k's per block)
// [16,128): PWT [1024x448]  [128,384): E1   [384,640): W12t   [640,1664): prep_x
__global__ __launch_bounds__(256) void mid_all(
    const float* __restrict__ x_num, const int* __restrict__ x_cat,
    const int* __restrict__ t_in, const float* __restrict__ noise,
    const float* __restrict__ gum, const float* __restrict__ sched,
    __hip_bfloat16* __restrict__ X, int* __restrict__ hot,
    const __hip_bfloat16* __restrict__ w1t, const __hip_bfloat16* __restrict__ pjb,
    const __hip_bfloat16* __restrict__ tw2b, const __hip_bfloat16* __restrict__ E0,
    const __hip_bfloat16* __restrict__ tw1t,
    const float* __restrict__ te_b1, const float* __restrict__ zbias,
    __hip_bfloat16* __restrict__ PWT, __hip_bfloat16* __restrict__ E1,
    __hip_bfloat16* __restrict__ W12t,
    const float* __restrict__ colconst, const float* __restrict__ mlp_b1,
    float* __restrict__ bias2) {
    __shared__ __align__(16) char SM[8192];
    const int bid = blockIdx.x, tid = threadIdx.x;
    if (bid < 16) {
        // ---- bias2: per wave, 16 k's; per k: 64-lane dot over 1024 elements
        const int lane = tid & 63, wave = tid >> 6;
        for (int kk = 0; kk < 16; ++kk) {
            int k = bid * 64 + wave * 16 + kk;
            const __hip_bfloat16* row = w1t + (size_t)k * 1024 + lane * 16;
            const float* cc = colconst + lane * 16;
            float s = 0.0f;
#pragma unroll
            for (int q = 0; q < 16; ++q)
                s = fmaf(__bfloat162float(row[q]), cc[q], s);
            for (int off = 32; off > 0; off >>= 1)
                s += __shfl_down(s, off);
            if (lane == 0) bias2[k] = s + mlp_b1[k];
        }
    } else if (bid < 128) {
        // ---- PWT[j,k] = sum_n w1[n,j] proj_w[k,n] -> [1024 x 448] (cols 416+ = 0)
        int lb = bid - 16;
        gemm64_body(false, w1t, pjb, zbias, PWT, 1024, 1024, 448, 448,
                    lb / 7, lb % 7, SM, tid);
    } else if (bid < 384) {
        // ---- E1 = silu(E0 @ te_w1 + te_b1)  [1000 x 1024]
        int lb = bid - 128;
        gemm64_body(true, E0, tw1t, te_b1, E1, 1000, 1024, 1024, 1024,
                    lb >> 4, lb & 15, SM, tid);
    } else if (bid < 640) {
        // ---- W12t[k,n] = sum_j w1[j,k] te_w2[n,j]  ( = (te_w2@w1)^T )
        int lb = bid - 384;
        gemm64_body(false, w1t, tw2b, zbias, W12t, 1024, 1024, 1024, 1024,
                    lb >> 4, lb & 15, SM, tid);
    } else {
        // ---- prep_x: gumbel argmax + build X[B x 448] bf16 (cols 416+ = 0)
        float* xnt = (float*)SM;                    // [16][16]
        int* sh_hot = (int*)(SM + 1024);            // [16][24]
        int* sh_t = (int*)(SM + 1024 + 1536);       // [16]
        const int b0 = (bid - 640) * 16;
        const float* LOG_CA = sched + 2000;
        const float* LOG_1M_CA = sched + 3000;
        const float* SQ_AC = sched + 4000;
        const float* SQ_1M = sched + 5000;
        if (tid < 16) sh_t[tid] = t_in[b0 + tid];
        __syncthreads();
        {
            int r = tid >> 4, i = tid & 15;
            int t = sh_t[r];
            xnt[r * 16 + i] = SQ_AC[t] * x_num[(size_t)(b0 + r) * 16 + i] +
                              SQ_1M[t] * noise[(size_t)(b0 + r) * 16 + i];
        }
        for (int task = tid; task < 16 * 24; task += 256) {
            int r = task / 24, c = task - r * 24;
            int t = sh_t[r];
            int xc = x_cat[(size_t)(b0 + r) * 24 + c];
            float l1 = LOG_1M_CA[t] - LOGKF;
            float lca = LOG_CA[t];
            float vh = lae(lca, l1);
            float vo = lae(L30F + lca, l1);
            const float* gu = gum + (size_t)(b0 + r) * 384 + c * 16;
            float best = -3.0e38f;
            int bi = 0;
#pragma unroll
            for (int k = 0; k < 16; ++k) {
                float g = -logf(-logf(gu[k] + 1e-30f) + 1e-30f);
                float v = g + ((k == xc) ? vh : vo);
                if (v > best) { best = v; bi = k; }
            }
            sh_hot[r * 24 + c] = bi;
            hot[(size_t)(b0 + r) * 24 + c] = bi;
        }
        __syncthreads();
        const float DELTA = 69.07755279f;  // -L30F
#pragma unroll
        for (int it = 0; it < 4; ++it) {
            int idx = it * 256 + tid;          // 16*56 = 896 short8 stores
            if (idx < 896) {
                int r = idx / 56, jc = idx - r * 56;
                int j0 = jc * 8;
                __hip_bfloat16 v[8];
#pragma unroll
                for (int qq = 0; qq < 8; ++qq) {
                    int j = j0 + qq;
                    float f = 0.0f;
                    if (j < 16) {
                        f = xnt[r * 16 + j];
                    } else if (j < 400) {
                        int c = (j - 16) >> 4, k = (j - 16) & 15;
                        f = (sh_hot[r * 24 + c] == k) ? DELTA : 0.0f;
                    }
                    v[qq] = __float2bfloat16(f);
                }
                *(short8*)(X + (size_t)(b0 + r) * 448 + j0) = *(const short8*)v;
            }
        }
    }
}

// ------------------------------------------------------------ bf16 MFMA GEMM
// EPI 5 = plain bf16 store (BK=32). Used for EMB2 only.
template <int EPI, int TILE>
__global__ __launch_bounds__(256) void gemm_mfma(
    const __hip_bfloat16* __restrict__ A, const __hip_bfloat16* __restrict__ Bt,
    const float* __restrict__ bias, void* __restrict__ Cout,
    int M, int Kd, int Nreal, int Cstride,
    const int* __restrict__ tidx, const float* __restrict__ rowbias) {
    constexpr int FM  = TILE / 32;
    constexpr int CPM2 = TILE / 16;
    constexpr int CPW2 = CPM2 / 2;
    constexpr int STAGE = 4 * TILE * 32;
    __shared__ __align__(16) char SMEM[STAGE];
    __hip_bfloat16* As = (__hip_bfloat16*)SMEM;
    __hip_bfloat16* Bs = As + TILE * 32;

    const int tid = threadIdx.x;
    const int lane = tid & 63, wave = tid >> 6;
    const int wm = wave >> 1, wn = wave & 1;

    int mb, nb;
    {
        int nbx = gridDim.x, nby = gridDim.y;
        int b = blockIdx.y * nbx + blockIdx.x;
        if ((nby & 7) == 0) {
            int x = b & 7, g = b >> 3;
            nb = g % nbx;
            mb = x + 8 * (g / nbx);
        } else { mb = blockIdx.y; nb = blockIdx.x; }
    }
    const int m0 = mb * TILE, n0 = nb * TILE;

    const __hip_bfloat16* gsrc[CPW2];
    char* ldst[CPW2];
#pragma unroll
    for (int ii = 0; ii < CPW2; ++ii) {
        int gc = wave * CPW2 + ii;
        int mat = gc / CPM2, rc = gc % CPM2;
        int row = rc * 16 + (lane >> 2);
        int col = (lane & 3) * 8;
        size_t loff = (size_t)rc * 16 * 32 * 2;
        if (mat == 0) {
            int r = m0 + row; if (r > M - 1) r = M - 1;
            gsrc[ii] = A + (size_t)r * Kd + col;
            ldst[ii] = (char*)As + loff;
        } else {
            int r = n0 + row;
            gsrc[ii] = Bt + (size_t)r * Kd + col;
            ldst[ii] = (char*)Bs + loff;
        }
    }

    f32x4 acc[FM][FM] = {};
    const int q8 = (lane >> 4) * 8;
    const int l15 = lane & 15;

    for (int k0 = 0; k0 < Kd; k0 += 32) {
#pragma unroll
        for (int ii = 0; ii < CPW2; ++ii) glds16(gsrc[ii] + k0, ldst[ii]);
        __syncthreads();
        short8 af[FM], bfr[FM];
#pragma unroll
        for (int i = 0; i < FM; ++i) {
            af[i]  = *(const short8*)(As + (size_t)(wm * (TILE / 2) + i * 16 + l15) * 32 + q8);
            bfr[i] = *(const short8*)(Bs + (size_t)(wn * (TILE / 2) + i * 16 + l15) * 32 + q8);
        }
#pragma unroll
        for (int i = 0; i < FM; ++i)
#pragma unroll
            for (int j = 0; j < FM; ++j)
                acc[i][j] = __builtin_amdgcn_mfma_f32_16x16x32_bf16(
                    af[i], bfr[j], acc[i][j], 0, 0, 0);
        __syncthreads();
    }

#pragma unroll
    for (int i = 0; i < FM; ++i) {
        int mlbase = wm * (TILE / 2) + i * 16 + (lane >> 4) * 4;
#pragma unroll
        for (int j = 0; j < FM; ++j) {
            int nl = wn * (TILE / 2) + j * 16 + l15;
            int n = n0 + nl;
            if (n >= Nreal) continue;
            float bv = bias[n];
#pragma unroll
            for (int r = 0; r < 4; ++r) {
                int ml = mlbase + r;
                int m = m0 + ml;
                if (m >= M) continue;
                float v = acc[i][j][r] + bv;
                ((__hip_bfloat16*)Cout)[(size_t)m * Cstride + n] = __float2bfloat16(v);
            }
        }
    }
}

// --------------------- z-GEMM: 128x64 tile, BK=64, emb+relu epilogue ---------
// R[m, n] = relu( X[m,:] @ PWT[n,:]^T + EMB2[t[m]][n] ). grid dim3(16, 128).
__global__ __launch_bounds__(256) void gemm_z(
    const __hip_bfloat16* __restrict__ A, const __hip_bfloat16* __restrict__ Bt,
    __hip_bfloat16* __restrict__ C, int Kd, int Cstride,
    const int* __restrict__ tidx, const __hip_bfloat16* __restrict__ emb) {
    constexpr int TM = 128, TN = 64, BK = 64;
    constexpr int KCH = BK / 32;                 // 2
    constexpr int CPMA = KCH * (TM / 16);        // 16 A chunks
    constexpr int CPMB = KCH * (TN / 16);        // 8 B chunks
    constexpr int CPW = (CPMA + CPMB) / 4;       // 6 per wave
    constexpr int STAGE = (TM + TN) * BK * 2;    // 24576 B
    __shared__ __align__(16) char SMEM[STAGE + TM * TN * 2];   // + 16 KB emb tile
    __hip_bfloat16* As = (__hip_bfloat16*)SMEM;          // [KCH][TM][32]
    __hip_bfloat16* Bs = As + KCH * TM * 32;             // [KCH][TN][32]
    __hip_bfloat16* LE = (__hip_bfloat16*)(SMEM + STAGE);  // [TM][TN]

    const int tid = threadIdx.x;
    const int lane = tid & 63, wave = tid >> 6;
    const int wm = wave >> 1, wn = wave & 1;             // wave tile 64x32

    // XCD swizzle
    int mb, nb;
    {
        int nbx = gridDim.x;
        int b = blockIdx.y * nbx + blockIdx.x;
        int x = b & 7, g = b >> 3;
        nb = g % nbx;
        mb = x + 8 * (g / nbx);
    }
    const int m0 = mb * TM, n0 = nb * TN;

    const __hip_bfloat16* gsrc[CPW];
    char* ldst[CPW];
#pragma unroll
    for (int ii = 0; ii < CPW; ++ii) {
        int gc = wave * CPW + ii;
        if (gc < CPMA) {
            int h = gc / (TM / 16), rc = gc % (TM / 16);
            int row = rc * 16 + (lane >> 2);
            int col = h * 32 + (lane & 3) * 8;
            gsrc[ii] = A + (size_t)(m0 + row) * Kd + col;
            ldst[ii] = (char*)As + ((size_t)h * TM * 32 + (size_t)rc * 16 * 32) * 2;
        } else {
            int rem = gc - CPMA;
            int h = rem / (TN / 16), rc = rem % (TN / 16);
            int row = rc * 16 + (lane >> 2);
            int col = h * 32 + (lane & 3) * 8;
            gsrc[ii] = Bt + (size_t)(n0 + row) * Kd + col;
            ldst[ii] = (char*)Bs + ((size_t)h * TN * 32 + (size_t)rc * 16 * 32) * 2;
        }
    }

    // Gather 128 EMB2 rows (64 bf16 = 128 B each) into LE, batched: per wave
    // 32 rows via 4 glds16 (each = 8 rows x 8 lanes x 16 B). Per-lane global
    // address, wave-uniform LDS base; drained by the K-loop's first barrier.
    {
        int tvec = tidx[m0 + wave * 32 + (lane & 31)];
#pragma unroll
        for (int b = 0; b < 4; ++b) {
            int trow = __shfl(tvec, b * 8 + (lane >> 3));
            glds16((const char*)(emb + (size_t)trow * 1024 + n0) + (lane & 7) * 16,
                   (char*)LE + (wave * 32 + b * 8) * 128);
        }
    }

    f32x4 acc[4][2] = {};
    const int q8 = (lane >> 4) * 8;
    const int l15 = lane & 15;

    for (int k0 = 0; k0 < Kd; k0 += BK) {
#pragma unroll
        for (int ii = 0; ii < CPW; ++ii) glds16(gsrc[ii] + k0, ldst[ii]);
        __syncthreads();
#pragma unroll
        for (int kk = 0; kk < KCH; ++kk) {
            short8 af[4], bfr[2];
#pragma unroll
            for (int i = 0; i < 4; ++i)
                af[i] = *(const short8*)(As + (size_t)kk * TM * 32 +
                                         (size_t)(wm * 64 + i * 16 + l15) * 32 + q8);
#pragma unroll
            for (int j = 0; j < 2; ++j)
                bfr[j] = *(const short8*)(Bs + (size_t)kk * TN * 32 +
                                          (size_t)(wn * 32 + j * 16 + l15) * 32 + q8);
#pragma unroll
            for (int i = 0; i < 4; ++i)
#pragma unroll
                for (int j = 0; j < 2; ++j)
                    acc[i][j] = __builtin_amdgcn_mfma_f32_16x16x32_bf16(
                        af[i], bfr[j], acc[i][j], 0, 0, 0);
        }
        __syncthreads();
    }

#pragma unroll
    for (int i = 0; i < 4; ++i) {
        int mlbase = wm * 64 + i * 16 + (lane >> 4) * 4;
#pragma unroll
        for (int j = 0; j < 2; ++j) {
            int nl = wn * 32 + j * 16 + l15;
            int n = n0 + nl;
#pragma unroll
            for (int r = 0; r < 4; ++r) {
                int ml = mlbase + r;
                int m = m0 + ml;
                float v = acc[i][j][r] + __bfloat162float(LE[ml * TN + nl]);
                v = fmaxf(v, 0.0f);
                C[(size_t)m * Cstride + n] = __float2bfloat16(v);
            }
        }
    }
}

// --------------------- fused loss GEMM: 128x64 tile, BK=64 -------------------
// (R[M,1024] @ w2t^T + mlp_b2) -> LDS scoreboard S[128][64] -> per-(row,cat)
// linear-space loss -> atomicAdd. grid dim3(7, 128). ltbl = per-t loss table.
__global__ __launch_bounds__(256) void gemm_loss(
    const __hip_bfloat16* __restrict__ A, const __hip_bfloat16* __restrict__ Bt,
    const float* __restrict__ bias, int M, int Kd,
    const float* __restrict__ ltbl,
    const int* __restrict__ x_cat, const int* __restrict__ t_in,
    const int* __restrict__ hot, const float* __restrict__ noise,
    double* __restrict__ acc_out) {
    constexpr int TM = 128, TN = 64, BK = 64;
    constexpr int KCH = BK / 32;                 // 2
    constexpr int CPMA = KCH * (TM / 16);        // 16 A chunks
    constexpr int CPMB = KCH * (TN / 16);        // 8 B chunks
    constexpr int CPW = (CPMA + CPMB) / 4;       // 6 per wave
    constexpr int STAGE = (TM + TN) * BK * 2;    // 24576 B
    constexpr int SCORE = TM * TN * 4;           // 32768 B
    __shared__ __align__(16) char SMEM[SCORE > STAGE ? SCORE : STAGE];
    __hip_bfloat16* As = (__hip_bfloat16*)SMEM;          // [KCH][TM][32]
    __hip_bfloat16* Bs = As + KCH * TM * 32;             // [KCH][TN][32]

    const int tid = threadIdx.x;
    const int lane = tid & 63, wave = tid >> 6;
    const int wm = wave >> 1, wn = wave & 1;             // wave tile 64x32

    // XCD swizzle
    int mb, nb;
    {
        int nbx = gridDim.x;
        int b = blockIdx.y * nbx + blockIdx.x;
        int x = b & 7, g = b >> 3;
        nb = g % nbx;
        mb = x + 8 * (g / nbx);
    }
    const int m0 = mb * TM, n0 = nb * TN;

    const __hip_bfloat16* gsrc[CPW];
    char* ldst[CPW];
#pragma unroll
    for (int ii = 0; ii < CPW; ++ii) {
        int gc = wave * CPW + ii;
        int row, col;
        if (gc < CPMA) {
            int h = gc / (TM / 16), rc = gc % (TM / 16);
            row = rc * 16 + (lane >> 2);
            col = h * 32 + (lane & 3) * 8;
            gsrc[ii] = A + (size_t)(m0 + row) * Kd + col;
            ldst[ii] = (char*)As + ((size_t)h * TM * 32 + (size_t)rc * 16 * 32) * 2;
        } else {
            int rem = gc - CPMA;
            int h = rem / (TN / 16), rc = rem % (TN / 16);
            row = rc * 16 + (lane >> 2);
            col = h * 32 + (lane & 3) * 8;
            gsrc[ii] = Bt + (size_t)(n0 + row) * Kd + col;
            ldst[ii] = (char*)Bs + ((size_t)h * TN * 32 + (size_t)rc * 16 * 32) * 2;
        }
    }

    f32x4 acc[4][2] = {};
    const int q8 = (lane >> 4) * 8;
    const int l15 = lane & 15;

    for (int k0 = 0; k0 < Kd; k0 += BK) {
#pragma unroll
        for (int ii = 0; ii < CPW; ++ii) glds16(gsrc[ii] + k0, ldst[ii]);
        __syncthreads();
#pragma unroll
        for (int kk = 0; kk < KCH; ++kk) {
            short8 af[4], bfr[2];
#pragma unroll
            for (int i = 0; i < 4; ++i)
                af[i] = *(const short8*)(As + (size_t)kk * TM * 32 +
                                         (size_t)(wm * 64 + i * 16 + l15) * 32 + q8);
#pragma unroll
            for (int j = 0; j < 2; ++j)
                bfr[j] = *(const short8*)(Bs + (size_t)kk * TN * 32 +
                                          (size_t)(wn * 32 + j * 16 + l15) * 32 + q8);
#pragma unroll
            for (int i = 0; i < 4; ++i)
#pragma unroll
                for (int j = 0; j < 2; ++j)
                    acc[i][j] = __builtin_amdgcn_mfma_f32_16x16x32_bf16(
                        af[i], bfr[j], acc[i][j], 0, 0, 0);
        }
        __syncthreads();
    }

    // Phase 1: dump acc to scoreboard S[128][64], swizzle col' = (col+row)&63.
    float* S = (float*)SMEM;
#pragma unroll
    for (int i = 0; i < 4; ++i) {
        int rbase = wm * 64 + i * 16 + (lane >> 4) * 4;
#pragma unroll
        for (int j = 0; j < 2; ++j) {
            int lcol = wn * 32 + j * 16 + l15;
#pragma unroll
            for (int r = 0; r < 4; ++r) {
                int row = rbase + r;
                S[row * TN + ((lcol + row) & (TN - 1))] = acc[i][j][r];
            }
        }
    }
    __syncthreads();

    // Phase 2: one (row, 16-col-group) pair per thread iter (512 pairs).
    double local = 0.0;
    for (int p = tid; p < TM * (TN / 16); p += 256) {
        int ml = p & (TM - 1), cg = p / TM;
        int colbase = n0 + cg * 16;
        if (colbase >= 400) continue;
        int m = m0 + ml;
        float ocv[16];
#pragma unroll
        for (int k = 0; k < 16; ++k)
            ocv[k] = S[ml * TN + ((cg * 16 + k + ml) & (TN - 1))] + bias[colbase + k];
        if (colbase == 0) {
#pragma unroll
            for (int k = 0; k < 16; ++k) {
                float d = noise[(size_t)m * 16 + k] - ocv[k];
                local += (double)(d * d) * (1.0 / (16.0 * BATCH));
            }
        } else {
            int c = (colbase - 16) >> 4;
            int t = t_in[m];
            int xc = x_cat[m * 24 + c];
            int s = hot[m * 24 + c];
            const float* tb = ltbl + t * 8;
            float A1 = tb[0], B1 = tb[1], B1p = tb[2], Qh = tb[3], Qo = tb[4];
            float mx = -3e38f;
#pragma unroll
            for (int k = 0; k < 16; ++k) mx = fmaxf(mx, ocv[k]);
            float E[16];
            float sm = 0.0f;
#pragma unroll
            for (int k = 0; k < 16; ++k) { E[k] = expf(ocv[k] - mx); sm += E[k]; }
            float A1s = A1 / sm;
            float SU = 0.0f, slU = 0.0f, lUxc = 0.0f, lUs = 0.0f;
#pragma unroll
            for (int k = 0; k < 16; ++k) {
                float U = (E[k] * A1s + B1) * ((k == s) ? Qh : Qo);
                SU += U;
                float l = logf(fmaxf(U, 1e-37f));
                slU += l;
                if (k == xc) lUxc = l;
                if (k == s)  lUs = l;
            }
            float lSU = logf(SU);
            float Wh, Ws, Wo, C;
            if (t == 0) {
                Wh = 1.0f; Ws = 1e-30f; Wo = 1e-30f; C = 0.0f;
            } else {
                int e = (xc == s);
                float UTh = (A1 + B1) * (e ? Qh : Qo);
                float UTs = B1p * Qh;
                float UTo = B1p * Qo;
                float ST = e ? (UTh + 15.0f * UTo) : (UTh + UTs + 14.0f * UTo);
                float rST = 1.0f / ST;
                Wh = UTh * rST; Wo = UTo * rST; Ws = UTs * rST;
                C = e ? tb[6] : tb[5];
            }
            float wsTerm = (xc == s) ? 0.0f : (Ws - Wo);
            float SPU = Wo * slU + (Wh - Wo) * lUxc + wsTerm * lUs;
            float Lt = C - SPU + lSU;
            local += (double)Lt * (1.0 / (24.0 * BATCH));
        }
    }
    for (int off = 32; off > 0; off >>= 1)
        local += __shfl_down(local, off);
    __syncthreads();
    double* wred = (double*)SMEM;
    if (lane == 0) wred[wave] = local;
    __syncthreads();
    if (tid == 0)
        atomicAdd(acc_out, wred[0] + wred[1] + wred[2] + wred[3]);
}

__global__ void finalize_kernel(const double* __restrict__ acc,
                                const float* __restrict__ sched,
                                float* __restrict__ out) {
    // kl_prior is identical for every (sample, category): add once.
    float lcaT = sched[2999];
    float l1mT = sched[3999] - LOGKF;
    float ph = lae(lcaT, l1mT);
    float po = lae(L30F + lcaT, l1mT);
    float prior = expf(ph) * (ph + LOGKF) + 15.0f * expf(po) * (po + LOGKF);
    out[0] = (float)(*acc + (double)prior);
}

extern "C" void kernel_launch(void* const* d_in, const int* in_sizes, int n_in,
                              void* d_out, int out_size, void* d_ws, size_t ws_size,
                              hipStream_t stream) {
    const float* x_num  = (const float*)d_in[0];
    const int*   x_cat  = (const int*)d_in[1];
    const int*   t_in   = (const int*)d_in[2];
    const float* noise  = (const float*)d_in[3];
    const float* gum    = (const float*)d_in[4];
    const float* te_w1  = (const float*)d_in[5];
    const float* te_b1  = (const float*)d_in[6];
    const float* te_w2  = (const float*)d_in[7];
    const float* te_b2  = (const float*)d_in[8];
    const float* proj_w = (const float*)d_in[9];
    const float* proj_b = (const float*)d_in[10];
    const float* mlp_w1 = (const float*)d_in[11];
    const float* mlp_b1 = (const float*)d_in[12];
    const float* mlp_w2 = (const float*)d_in[13];
    const float* mlp_b2 = (const float*)d_in[14];
    float* out = (float*)d_out;

    char* w = (char*)d_ws;
    size_t off = 0;
    auto alloc = [&](size_t bytes) {
        void* p = w + off;
        off += (bytes + 1023) & ~(size_t)1023;
        return p;
    };
    double* acc     = (double*)alloc(1024);
    float* sched    = (float*)alloc(6 * 1000 * 4);
    float* ltbl     = (float*)alloc(8 * 1000 * 4);
    int*   hot      = (int*)alloc((size_t)BATCH * 24 * 4);
    float* colconst = (float*)alloc(1024 * 4);
    float* zbias    = (float*)alloc(1024 * 4);
    float* bias2    = (float*)alloc(1024 * 4);
    __hip_bfloat16* E0    = (__hip_bfloat16*)alloc((size_t)1024 * 1024 * 2);
    __hip_bfloat16* E1    = (__hip_bfloat16*)alloc((size_t)1024 * 1024 * 2);
    __hip_bfloat16* EMB2  = (__hip_bfloat16*)alloc((size_t)1024 * 1024 * 2);
    __hip_bfloat16* tw1t  = (__hip_bfloat16*)alloc((size_t)1024 * 1024 * 2);
    __hip_bfloat16* tw2b  = (__hip_bfloat16*)alloc((size_t)1024 * 1024 * 2);
    __hip_bfloat16* W12t  = (__hip_bfloat16*)alloc((size_t)1024 * 1024 * 2);
    __hip_bfloat16* w1t   = (__hip_bfloat16*)alloc((size_t)1024 * 1024 * 2);
    __hip_bfloat16* w2t   = (__hip_bfloat16*)alloc((size_t)512 * 1024 * 2);
    __hip_bfloat16* pjb   = (__hip_bfloat16*)alloc((size_t)448 * 1024 * 2);
    __hip_bfloat16* PWT   = (__hip_bfloat16*)alloc((size_t)1024 * 448 * 2);
    __hip_bfloat16* X     = (__hip_bfloat16*)alloc((size_t)BATCH * 448 * 2);
    __hip_bfloat16* R     = (__hip_bfloat16*)alloc((size_t)BATCH * 1024 * 2);

    // 1) setup: transposes + casts + E0 + colconst + schedules/ltbl + acc zero
    setup_all<<<7301, 256, 0, stream>>>(te_w1, mlp_w1, mlp_w2, te_w2,
                                        tw1t, w1t, w2t, pjb, tw2b,
                                        E0, proj_w, proj_b, te_b2,
                                        colconst, zbias, sched, ltbl, acc);
    // 2) mid: bias2 + PWT + E1 + W12t + prep_x
    mid_all<<<1664, 256, 0, stream>>>(x_num, x_cat, t_in, noise, gum, sched, X, hot,
                                      w1t, pjb, tw2b, E0, tw1t, te_b1, zbias,
                                      PWT, E1, W12t, colconst, mlp_b1, bias2);
    // 3) EMB2 = E1 @ W12t^T + bias2   [per-t hidden-layer bias table]
    gemm_mfma<5, 64><<<dim3(16, 16), 256, 0, stream>>>(
        E1, W12t, bias2, EMB2, 1000, 1024, 1024, 1024, nullptr, nullptr);
    // 4) R = relu(X @ PWT^T + EMB2[t])   [128x64 tile, BK=64, K=448]
    gemm_z<<<dim3(16, 128), 256, 0, stream>>>(
        X, PWT, R, 448, 1024, t_in, EMB2);
    // 5) loss: 128x64 tile, BK=64 -> scoreboard -> linear-space loss
    gemm_loss<<<dim3(7, 128), 256, 0, stream>>>(
        R, w2t, mlp_b2, BATCH, 1024, ltbl, x_cat, t_in, hot, noise, acc);
    // 6) finalize
    finalize_kernel<<<1, 1, 0, stream>>>(acc, sched, out);
}